// Round 15
// baseline (191.495 us; speedup 1.0000x reference)
//
#include <hip/hip_runtime.h>

typedef __bf16 bf16;
typedef __bf16 bf16x8 __attribute__((ext_vector_type(8)));
typedef __bf16 bf16x4 __attribute__((ext_vector_type(4)));
typedef float f32x4 __attribute__((ext_vector_type(4)));

__device__ __forceinline__ void gload_lds16(const void* g, void* l) {
  __builtin_amdgcn_global_load_lds(
      (const __attribute__((address_space(1))) unsigned int*)g,
      (__attribute__((address_space(3))) unsigned int*)l, 16, 0, 0);
}

// ---- prologue: LN1 + wq/wk/wv/wo transposes (w1/w2 ride inside the QKV GEMM) -------
__global__ __launch_bounds__(256) void prep_kernel(
    const float* __restrict__ wq, const float* __restrict__ wk,
    const float* __restrict__ wv, const float* __restrict__ wo,
    bf16* __restrict__ wTqkv, bf16* __restrict__ wTo,
    const float* __restrict__ x, const float* __restrict__ g,
    const float* __restrict__ b, bf16* __restrict__ y) {
  const int id = blockIdx.x;
  if (id < 1024) {  // ---- LN1 ----
    const int w = threadIdx.x >> 6, lane = threadIdx.x & 63;
    const int row = id * 4 + w;
    const float* xr = x + (size_t)row * 1024;
    float4 v[4];
    float s = 0.f, sq = 0.f;
#pragma unroll
    for (int c = 0; c < 4; c++) {
      v[c] = *reinterpret_cast<const float4*>(xr + c * 256 + lane * 4);
      s += v[c].x + v[c].y + v[c].z + v[c].w;
      sq += v[c].x * v[c].x + v[c].y * v[c].y + v[c].z * v[c].z + v[c].w * v[c].w;
    }
#pragma unroll
    for (int d = 32; d >= 1; d >>= 1) {
      s += __shfl_xor(s, d, 64);
      sq += __shfl_xor(sq, d, 64);
    }
    const float mu = s * (1.f / 1024.f);
    const float rs = rsqrtf(sq * (1.f / 1024.f) - mu * mu + 1e-6f);
#pragma unroll
    for (int c = 0; c < 4; c++) {
      float4 gv = *reinterpret_cast<const float4*>(g + c * 256 + lane * 4);
      float4 bv = *reinterpret_cast<const float4*>(b + c * 256 + lane * 4);
      bf16x4 ov;
      ov[0] = (bf16)((v[c].x - mu) * rs * gv.x + bv.x);
      ov[1] = (bf16)((v[c].y - mu) * rs * gv.y + bv.y);
      ov[2] = (bf16)((v[c].z - mu) * rs * gv.z + bv.z);
      ov[3] = (bf16)((v[c].w - mu) * rs * gv.w + bv.w);
      *reinterpret_cast<bf16x4*>(y + (size_t)row * 1024 + c * 256 + lane * 4) = ov;
    }
    return;
  }
  __shared__ float tile[32][33];
  const int idx = id - 1024;
  const int m = idx >> 10, r = idx & 1023;
  const float* src = m == 0 ? wq : m == 1 ? wk : m == 2 ? wv : wo;
  bf16* dst = m == 3 ? wTo : wTqkv + (size_t)m * 1024 * 1024;
  const int tx = threadIdx.x & 31, ty = threadIdx.x >> 5;
  const int c0 = (r & 31) * 32, r0 = (r >> 5) * 32;
#pragma unroll
  for (int i = 0; i < 4; i++)
    tile[ty + i * 8][tx] = src[(size_t)(r0 + ty + i * 8) * 1024 + c0 + tx];
  __syncthreads();
#pragma unroll
  for (int i = 0; i < 4; i++)
    dst[(size_t)(c0 + ty + i * 8) * 1024 + r0 + tx] = (bf16)tile[tx][ty + i * 8];
}

// ---- fused reduce (o-proj split-K=2 partials) + residual + LayerNorm -----------------
__global__ __launch_bounds__(256) void reduce_ln_kernel(const bf16* __restrict__ p0,
                                                        const bf16* __restrict__ p1,
                                                        const float* __restrict__ x,
                                                        const float* __restrict__ g,
                                                        const float* __restrict__ b,
                                                        bf16* __restrict__ xres,
                                                        bf16* __restrict__ y) {
  const int w = threadIdx.x >> 6, lane = threadIdx.x & 63;
  const int row = blockIdx.x * 4 + w;
  const size_t rb = (size_t)row * 1024;
  float4 v[4];
  float s = 0.f, sq = 0.f;
#pragma unroll
  for (int c = 0; c < 4; c++) {
    const int off = c * 256 + lane * 4;
    float4 xv = *reinterpret_cast<const float4*>(x + rb + off);
    bf16x4 a0 = *reinterpret_cast<const bf16x4*>(p0 + rb + off);
    bf16x4 a1 = *reinterpret_cast<const bf16x4*>(p1 + rb + off);
    v[c].x = xv.x + (float)a0[0] + (float)a1[0];
    v[c].y = xv.y + (float)a0[1] + (float)a1[1];
    v[c].z = xv.z + (float)a0[2] + (float)a1[2];
    v[c].w = xv.w + (float)a0[3] + (float)a1[3];
    bf16x4 xo;
    xo[0] = (bf16)v[c].x; xo[1] = (bf16)v[c].y;
    xo[2] = (bf16)v[c].z; xo[3] = (bf16)v[c].w;
    *reinterpret_cast<bf16x4*>(xres + rb + off) = xo;
    s += v[c].x + v[c].y + v[c].z + v[c].w;
    sq += v[c].x * v[c].x + v[c].y * v[c].y + v[c].z * v[c].z + v[c].w * v[c].w;
  }
#pragma unroll
  for (int d = 32; d >= 1; d >>= 1) {
    s += __shfl_xor(s, d, 64);
    sq += __shfl_xor(sq, d, 64);
  }
  const float mu = s * (1.f / 1024.f);
  const float rs = rsqrtf(sq * (1.f / 1024.f) - mu * mu + 1e-6f);
#pragma unroll
  for (int c = 0; c < 4; c++) {
    const int off = c * 256 + lane * 4;
    float4 gv = *reinterpret_cast<const float4*>(g + off);
    float4 bv = *reinterpret_cast<const float4*>(b + off);
    bf16x4 ov;
    ov[0] = (bf16)((v[c].x - mu) * rs * gv.x + bv.x);
    ov[1] = (bf16)((v[c].y - mu) * rs * gv.y + bv.y);
    ov[2] = (bf16)((v[c].z - mu) * rs * gv.z + bv.z);
    ov[3] = (bf16)((v[c].w - mu) * rs * gv.w + bv.w);
    *reinterpret_cast<bf16x4*>(y + rb + off) = ov;
  }
}

// ---- final reduce (FFN2 split-K partials) + bias + bf16 residual -> fp32 out ---------
__global__ __launch_bounds__(256) void reduce_out_kernel(const bf16* __restrict__ p0,
                                                         const bf16* __restrict__ p1,
                                                         const bf16* __restrict__ p2,
                                                         const bf16* __restrict__ p3,
                                                         const float* __restrict__ bias,
                                                         const bf16* __restrict__ xres,
                                                         float* __restrict__ out) {
  const size_t i = ((size_t)blockIdx.x * 256 + threadIdx.x) * 8;
  const int col = (int)(i & 1023);
  bf16x8 a0 = *reinterpret_cast<const bf16x8*>(p0 + i);
  bf16x8 a1 = *reinterpret_cast<const bf16x8*>(p1 + i);
  bf16x8 a2 = *reinterpret_cast<const bf16x8*>(p2 + i);
  bf16x8 a3 = *reinterpret_cast<const bf16x8*>(p3 + i);
  bf16x8 xr = *reinterpret_cast<const bf16x8*>(xres + i);
  float4 b0 = *reinterpret_cast<const float4*>(bias + col);
  float4 b1 = *reinterpret_cast<const float4*>(bias + col + 4);
  float4 o0, o1;
  o0.x = (float)xr[0] + b0.x + (float)a0[0] + (float)a1[0] + (float)a2[0] + (float)a3[0];
  o0.y = (float)xr[1] + b0.y + (float)a0[1] + (float)a1[1] + (float)a2[1] + (float)a3[1];
  o0.z = (float)xr[2] + b0.z + (float)a0[2] + (float)a1[2] + (float)a2[2] + (float)a3[2];
  o0.w = (float)xr[3] + b0.w + (float)a0[3] + (float)a1[3] + (float)a2[3] + (float)a3[3];
  o1.x = (float)xr[4] + b1.x + (float)a0[4] + (float)a1[4] + (float)a2[4] + (float)a3[4];
  o1.y = (float)xr[5] + b1.y + (float)a0[5] + (float)a1[5] + (float)a2[5] + (float)a3[5];
  o1.z = (float)xr[6] + b1.z + (float)a0[6] + (float)a1[6] + (float)a2[6] + (float)a3[6];
  o1.w = (float)xr[7] + b1.w + (float)a0[7] + (float)a1[7] + (float)a2[7] + (float)a3[7];
  *reinterpret_cast<float4*>(out + i) = o0;
  *reinterpret_cast<float4*>(out + i + 4) = o1;
}

// ---------------- 128^2 GEMM (2-phase) for o-proj (split-K, bf16 partials) ------------
template <int EPI>
__global__ __launch_bounds__(256) void gemm_bt(const bf16* __restrict__ A,
                                               const bf16* __restrict__ Bt,
                                               void* __restrict__ Cout,
                                               const float* __restrict__ bias,
                                               int M, int N, int K, int gy, int gxy,
                                               int Kc) {
  __shared__ __align__(16) bf16 As[2][128][32];
  __shared__ __align__(16) bf16 Bs[2][128][32];
  const int tid = threadIdx.x;
  const int w = tid >> 6, lane = tid & 63;
  const int wr = w >> 1, wc = w & 1;

  const int nwg = gridDim.x;
  const int cpx = nwg >> 3;
  const int swz = (blockIdx.x & 7) * cpx + (blockIdx.x >> 3);
  const int chunk = swz / gxy, rem = swz % gxy;
  const int gpc = gy << 3;
  const int band = rem / gpc, r2 = rem % gpc;
  const int bm = (band * 8 + (r2 & 7)) * 128;
  const int bn = (r2 >> 3) * 128;

  f32x4 acc[4][4] = {};
  const int r4 = lane >> 2;
  const int c8 = (lane & 3) * 8;
  const bf16* Ag = A + (size_t)(bm + w * 32 + r4) * K + chunk * Kc + c8;
  const bf16* Bg = Bt + (size_t)(bn + w * 32 + r4) * K + chunk * Kc + c8;
  const int fr = lane & 15, fo = (lane >> 4) * 8;

#define STAGE(buf, k0)                                                 \
  do {                                                                 \
    gload_lds16(Ag + (k0), &As[buf][w * 32][0]);                       \
    gload_lds16(Ag + (size_t)16 * K + (k0), &As[buf][w * 32 + 16][0]); \
    gload_lds16(Bg + (k0), &Bs[buf][w * 32][0]);                       \
    gload_lds16(Bg + (size_t)16 * K + (k0), &Bs[buf][w * 32 + 16][0]); \
  } while (0)

  const int nt = Kc >> 5;
  STAGE(0, 0);
  __syncthreads();
  int cur = 0;
  for (int t = 0; t < nt; ++t) {
    if (t + 1 < nt) STAGE(cur ^ 1, (t + 1) << 5);
    bf16x8 af[4], bfr[4];
#pragma unroll
    for (int m = 0; m < 4; m++)
      af[m] = *reinterpret_cast<const bf16x8*>(&As[cur][wr * 64 + m * 16 + fr][fo]);
#pragma unroll
    for (int n = 0; n < 4; n++)
      bfr[n] = *reinterpret_cast<const bf16x8*>(&Bs[cur][wc * 64 + n * 16 + fr][fo]);
#pragma unroll
    for (int m = 0; m < 4; m++)
#pragma unroll
      for (int n = 0; n < 4; n++)
        acc[m][n] = __builtin_amdgcn_mfma_f32_16x16x32_bf16(af[m], bfr[n], acc[m][n], 0, 0, 0);
    __syncthreads();
    cur ^= 1;
  }
#undef STAGE

  bf16* outp = (bf16*)Cout + (EPI == 3 ? (size_t)chunk * M * N : 0);
  const int cr = (lane >> 4) * 4, cc = lane & 15;
#pragma unroll
  for (int m = 0; m < 4; m++) {
#pragma unroll
    for (int n = 0; n < 4; n++) {
      const int row = bm + wr * 64 + m * 16 + cr;
      const int col = bn + wc * 64 + n * 16 + cc;
#pragma unroll
      for (int r = 0; r < 4; r++) {
        const float va = acc[m][n][r];
        const size_t idx = (size_t)(row + r) * N + col;
        if (EPI == 0 || EPI == 3) {
          outp[idx] = (bf16)va;
        } else {
          const float t = va + bias[col];
          outp[idx] = (bf16)(t > 0.f ? t : 0.f);
        }
      }
    }
  }
}

// ---------------- 256^2 8-phase GEMM; blocks >= ngemm run DEPTH-3 aux transposes ------
template <int EPI>
__global__ __launch_bounds__(512, 2) void gemm256(const bf16* __restrict__ A,
                                                  const bf16* __restrict__ Bt,
                                                  void* __restrict__ Cout,
                                                  const float* __restrict__ bias,
                                                  int M, int N, int K, int gy, int gxy,
                                                  int Kc, int ngemm,
                                                  const float* __restrict__ tw1,
                                                  const float* __restrict__ tw2,
                                                  bf16* __restrict__ two1,
                                                  bf16* __restrict__ two2) {
  __shared__ __align__(16) bf16 As[2][256][64];
  __shared__ __align__(16) bf16 Bs[2][256][64];
  const int tid = threadIdx.x;
  const int w = tid >> 6, lane = tid & 63;
  const int wm = w >> 2, wn = w & 3;
  const int fr = lane & 15, g = lane >> 4;

  const int nwg = gridDim.x;
  const int cpx = nwg >> 3;
  const int swz = (blockIdx.x & 7) * cpx + (blockIdx.x >> 3);

  char* AsB = (char*)&As[0][0][0];
  char* BsB = (char*)&Bs[0][0][0];

  if (swz >= ngemm) {
    // ---- aux: w1/w2 transposes, depth-3 float4 prefetch (latency fully hidden) ----
    const int aux = swz - ngemm;  // 0..63
    float* tf = (float*)AsB + (tid >> 8) * (33 * 32);
    const int t8 = tid & 255;
    const int sub = tid >> 8;              // 0..1
    const int lrow = t8 >> 3;              // load: row 0..31
    const int lcol = (t8 & 7) * 4;         //       float4 col
    const int tx = t8 & 31, ty = t8 >> 5;  // store: 32 x 8

    const float* src; bf16* dst; int R, C, c0, r0;
#define SETJOB(job)                                                     \
    do {                                                                \
      if ((job) < 4096) {                                               \
        src = tw1; dst = two1; R = 1024; C = 4096;                      \
        c0 = ((job) & 127) * 32; r0 = ((job) >> 7) * 32;                \
      } else {                                                          \
        const int j2 = (job) - 4096;                                    \
        src = tw2; dst = two2; R = 4096; C = 1024;                      \
        c0 = (j2 & 31) * 32; r0 = (j2 >> 5) * 32;                       \
      }                                                                 \
    } while (0)

    float4 f0, f1, f2;
    int c_0, r_0, R_0, c_1, r_1, R_1;
    bf16 *d_0, *d_1;

    SETJOB(aux * 2 + sub);
    f0 = *reinterpret_cast<const float4*>(&src[(size_t)(r0 + lrow) * C + c0 + lcol]);
    c_0 = c0; r_0 = r0; R_0 = R; d_0 = dst;
    SETJOB(128 + aux * 2 + sub);
    f1 = *reinterpret_cast<const float4*>(&src[(size_t)(r0 + lrow) * C + c0 + lcol]);
    c_1 = c0; r_1 = r0; R_1 = R; d_1 = dst;

    for (int t = 0; t < 64; ++t) {
      if (t + 2 < 64) {
        SETJOB((t + 2) * 128 + aux * 2 + sub);
        f2 = *reinterpret_cast<const float4*>(&src[(size_t)(r0 + lrow) * C + c0 + lcol]);
      }
      // scalar LDS writes at stride 33 (conflict-free; float4 would misalign)
      tf[lrow * 33 + lcol + 0] = f0.x;
      tf[lrow * 33 + lcol + 1] = f0.y;
      tf[lrow * 33 + lcol + 2] = f0.z;
      tf[lrow * 33 + lcol + 3] = f0.w;
      __syncthreads();
#pragma unroll
      for (int i = 0; i < 4; i++)
        d_0[(size_t)(c_0 + ty + i * 8) * R_0 + r_0 + tx] =
            (bf16)tf[tx * 33 + ty + i * 8];
      __syncthreads();
      f0 = f1; c_0 = c_1; r_0 = r_1; R_0 = R_1; d_0 = d_1;
      f1 = f2; c_1 = c0; r_1 = r0; R_1 = R; d_1 = dst;
    }
#undef SETJOB
    return;
  }

  const int chunk = swz / gxy, rem = swz % gxy;
  const int gpc = gy << 3;
  const int band = rem / gpc, r2 = rem % gpc;
  const int bm = (band * 8 + (r2 & 7)) * 256;
  const int bn = (r2 >> 3) * 256;

  const bf16* Ab = A + (size_t)bm * K;
  const bf16* Bb = Bt + (size_t)bn * K;

  const int lr = lane >> 3;
  const int sle = ((lane & 7) ^ lr) * 8;
  const int rB0 = w * 16;
  const int rB1 = 128 + w * 16;
  const int rA0 = wm * 128 + wn * 16;
  const int rA1 = wm * 128 + 64 + wn * 16;

  const int rowA = (wm * 128 + fr) * 128;
  const int rowB = (wn * 64 + fr) * 128;
  const int colk0 = (g * 16) ^ ((fr & 7) << 4);
  const int colk1 = (64 + g * 16) ^ ((fr & 7) << 4);

  f32x4 acc[8][4] = {};

#define SG8(base, r0, kb, ldsrow)                                           \
  do {                                                                      \
    gload_lds16(base + (size_t)((r0) + lr) * K + (kb) + sle, (ldsrow));     \
    gload_lds16(base + (size_t)((r0) + 8 + lr) * K + (kb) + sle,            \
                (char*)(ldsrow) + 1024);                                    \
  } while (0)

  const int nt = Kc >> 6;
  const int koff = chunk * Kc;

  SG8(Bb, rB0, koff, BsB + rB0 * 128);
  SG8(Bb, rB1, koff, BsB + rB1 * 128);
  SG8(Ab, rA0, koff, AsB + rA0 * 128);
  SG8(Ab, rA1, koff, AsB + rA1 * 128);

#define PHASE_BODY(p, mb)                                                     \
  {                                                                           \
    if ((p) == 0) {                                                           \
      _Pragma("unroll") for (int nf = 0; nf < 4; nf++) {                      \
        bfr[nf][0] = *(const bf16x8*)(Br + rowB + nf * 2048 + colk0);         \
        bfr[nf][1] = *(const bf16x8*)(Br + rowB + nf * 2048 + colk1);         \
      }                                                                       \
    }                                                                         \
    af[0][0] = *(const bf16x8*)(Ar + rowA + (mb)*2048 + colk0);               \
    af[0][1] = *(const bf16x8*)(Ar + rowA + (mb)*2048 + colk1);               \
    af[1][0] = *(const bf16x8*)(Ar + rowA + ((mb) + 1) * 2048 + colk0);       \
    af[1][1] = *(const bf16x8*)(Ar + rowA + ((mb) + 1) * 2048 + colk1);       \
    if (pre) {                                                                \
      if ((p) == 0) SG8(Bb, rB0, kb2, Bw + rB0 * 128);                        \
      if ((p) == 1) SG8(Bb, rB1, kb2, Bw + rB1 * 128);                        \
      if ((p) == 2) SG8(Ab, rA0, kb2, Aw + rA0 * 128);                        \
      if ((p) == 3) SG8(Ab, rA1, kb2, Aw + rA1 * 128);                        \
    }                                                                         \
    __builtin_amdgcn_s_setprio(1);                                            \
    _Pragma("unroll") for (int m2 = 0; m2 < 2; m2++)                          \
        _Pragma("unroll") for (int nf = 0; nf < 4; nf++) {                    \
      acc[(mb) + m2][nf] = __builtin_amdgcn_mfma_f32_16x16x32_bf16(           \
          af[m2][0], bfr[nf][0], acc[(mb) + m2][nf], 0, 0, 0);                \
      acc[(mb) + m2][nf] = __builtin_amdgcn_mfma_f32_16x16x32_bf16(           \
          af[m2][1], bfr[nf][1], acc[(mb) + m2][nf], 0, 0, 0);                \
    }                                                                         \
    __builtin_amdgcn_s_setprio(0);                                            \
  }

  int buf = 0;
  for (int kt = 0; kt < nt; ++kt) {
    char* Ar = AsB + buf * 32768;
    char* Br = BsB + buf * 32768;
    char* Aw = AsB + (buf ^ 1) * 32768;
    char* Bw = BsB + (buf ^ 1) * 32768;
    const bool pre = (kt + 1) < nt;
    const int kb2 = koff + (kt + 1) * 64;
    bf16x8 bfr[4][2];
    bf16x8 af[2][2];

    asm volatile("s_waitcnt vmcnt(2)" ::: "memory");
    __builtin_amdgcn_s_barrier();
    PHASE_BODY(0, 0)

    if (pre) asm volatile("s_waitcnt vmcnt(4)" ::: "memory");
    else     asm volatile("s_waitcnt vmcnt(2)" ::: "memory");
    __builtin_amdgcn_s_barrier();
    PHASE_BODY(1, 2)

    if (pre) asm volatile("s_waitcnt vmcnt(4)" ::: "memory");
    else     asm volatile("s_waitcnt vmcnt(0)" ::: "memory");
    __builtin_amdgcn_s_barrier();
    PHASE_BODY(2, 4)

    if (pre) asm volatile("s_waitcnt vmcnt(6)" ::: "memory");
    else     asm volatile("s_waitcnt vmcnt(0)" ::: "memory");
    __builtin_amdgcn_s_barrier();
    PHASE_BODY(3, 6)

    buf ^= 1;
  }
#undef PHASE_BODY
#undef SG8

  bf16* outp = (bf16*)Cout + (EPI == 3 ? (size_t)chunk * M * N : 0);
  const int cr = g * 4;
#pragma unroll
  for (int mf = 0; mf < 8; mf++) {
#pragma unroll
    for (int nf = 0; nf < 4; nf++) {
      const int row = bm + wm * 128 + mf * 16 + cr;
      const int col = bn + wn * 64 + nf * 16 + fr;
#pragma unroll
      for (int r = 0; r < 4; r++) {
        const float va = acc[mf][nf][r];
        const size_t idx = (size_t)(row + r) * N + col;
        if (EPI == 3 || EPI == 0) {
          outp[idx] = (bf16)va;
        } else {
          const float t = va + bias[col];
          outp[idx] = (bf16)(t > 0.f ? t : 0.f);
        }
      }
    }
  }
}

// ---------------- Flash attention v4: 8 waves x 16q, no-max softmax, unroll x2 --------
__global__ __launch_bounds__(512, 4) void attn_kernel(const bf16* __restrict__ Q,
                                                      const bf16* __restrict__ K,
                                                      const bf16* __restrict__ V,
                                                      bf16* __restrict__ O, int ld) {
  __shared__ __align__(16) bf16 Ks[2][64][64];
  __shared__ __align__(16) bf16 Vt[2][64][64];
  __shared__ __align__(16) bf16 Pl[8][16][64];
  const int tid = threadIdx.x;
  const int w = tid >> 6, l = tid & 63;
  const int lo = l & 15, g = l >> 4;
  const int sw = (lo & 7) << 3;

  const int id = blockIdx.x;
  const int bh = id & 63, qb = id >> 6;
  const int b = bh >> 4, h = bh & 15;
  const int hoff = h * 64;
  const size_t rowQ = (size_t)b * 1024 + qb * 128 + w * 16;
  const size_t rowKV0 = (size_t)b * 1024;

  const int srow = tid >> 3, scch = tid & 7;
  const int vcb = w * 8;

  bf16x8 qfr[2];
#pragma unroll
  for (int ds = 0; ds < 2; ds++)
    qfr[ds] = *reinterpret_cast<const bf16x8*>(
        Q + (rowQ + lo) * ld + hoff + ds * 32 + g * 8);

  const float c = 0.18033688f;  // 0.125 * log2(e)
  f32x4 lacc = {0.f, 0.f, 0.f, 0.f};
  f32x4 o[4] = {};

  {
    gload_lds16(K + (rowKV0 + srow) * ld + hoff + ((scch ^ (srow & 7)) << 3),
                &Ks[0][w * 8][0]);
    bf16x8 vv = *reinterpret_cast<const bf16x8*>(V + (rowKV0 + l) * ld + hoff + vcb);
#pragma unroll
    for (int j = 0; j < 8; j++) Vt[0][vcb + j][l ^ (j << 3)] = vv[j];
  }
  __syncthreads();

#define ATILE(PAR, KT)                                                               \
  {                                                                                  \
    bf16x8 vv;                                                                       \
    const bool more = (KT) + 1 < 16;                                                 \
    if (more) {                                                                      \
      const size_t rkv = rowKV0 + ((KT) + 1) * 64;                                   \
      gload_lds16(K + (rkv + srow) * ld + hoff + ((scch ^ (srow & 7)) << 3),         \
                  &Ks[(PAR) ^ 1][w * 8][0]);                                         \
      vv = *reinterpret_cast<const bf16x8*>(V + (rkv + l) * ld + hoff + vcb);        \
    }                                                                                \
    f32x4 sa[4] = {};                                                                \
    _Pragma("unroll") for (int ds = 0; ds < 2; ds++) {                               \
      bf16x8 kf[4];                                                                  \
      _Pragma("unroll") for (int kfi = 0; kfi < 4; kfi++)                            \
          kf[kfi] = *reinterpret_cast<const bf16x8*>(                                \
              &Ks[PAR][kfi * 16 + lo][(ds * 32 + g * 8) ^ sw]);                      \
      _Pragma("unroll") for (int kfi = 0; kfi < 4; kfi++)                            \
          sa[kfi] =                                                                  \
              __builtin_amdgcn_mfma_f32_16x16x32_bf16(kf[kfi], qfr[ds], sa[kfi], 0, 0, 0); \
    }                                                                                \
    float p[16];                                                                     \
    _Pragma("unroll") for (int kfi = 0; kfi < 4; kfi++)                              \
        _Pragma("unroll") for (int r = 0; r < 4; r++)                                \
            p[kfi * 4 + r] = exp2f(sa[kfi][r] * c);                                  \
    _Pragma("unroll") for (int r = 0; r < 4; r++)                                    \
        lacc[r] += (p[r] + p[4 + r]) + (p[8 + r] + p[12 + r]);                       \
    _Pragma("unroll") for (int kfi = 0; kfi < 4; kfi++) {                            \
      bf16x4 pk;                                                                     \
      pk[0] = (bf16)p[kfi * 4 + 0];                                                  \
      pk[1] = (bf16)p[kfi * 4 + 1];                                                  \
      pk[2] = (bf16)p[kfi * 4 + 2];                                                  \
      pk[3] = (bf16)p[kfi * 4 + 3];                                                  \
      *reinterpret_cast<bf16x4*>(&Pl[w][lo][(kfi * 16 + g * 4) ^ sw]) = pk;          \
    }                                                                                \
    _Pragma("unroll") for (int ks = 0; ks < 2; ks++) {                               \
      bf16x8 pf = *reinterpret_cast<const bf16x8*>(&Pl[w][lo][(ks * 32 + g * 8) ^ sw]); \
      _Pragma("unroll") for (int df = 0; df < 4; df++) {                             \
        bf16x8 vf = *reinterpret_cast<const bf16x8*>(                                \
            &Vt[PAR][df * 16 + lo][(ks * 32 + g * 8) ^ sw]);                         \
        o[df] = __builtin_amdgcn_mfma_f32_16x16x32_bf16(vf, pf, o[df], 0, 0, 0);     \
      }                                                                              \
    }                                                                                \
    if (more) {                                                                      \
      _Pragma("unroll") for (int j = 0; j < 8; j++)                                  \
          Vt[(PAR) ^ 1][vcb + j][l ^ (j << 3)] = vv[j];                              \
    }                                                                                \
    __syncthreads();                                                                 \
  }

  for (int kt2 = 0; kt2 < 16; kt2 += 2) {
    ATILE(0, kt2)
    ATILE(1, kt2 + 1)
  }
#undef ATILE

  float lsum = (lacc[0] + lacc[1]) + (lacc[2] + lacc[3]);
  lsum += __shfl_xor(lsum, 16);
  lsum += __shfl_xor(lsum, 32);
  const float rl = 1.f / lsum;
#pragma unroll
  for (int df = 0; df < 4; df++) {
    bf16x4 ov;
#pragma unroll
    for (int r = 0; r < 4; r++) ov[r] = (bf16)(o[df][r] * rl);
    *reinterpret_cast<bf16x4*>(&Pl[w][lo][(df * 16 + g * 4) ^ sw]) = ov;
  }
  const int row = l >> 2;
  const int swr = (row & 7) << 3;
  const int c2 = (l & 3) * 16;
#pragma unroll
  for (int i = 0; i < 2; i++) {
    bf16x8 ov = *reinterpret_cast<const bf16x8*>(&Pl[w][row][(c2 + i * 8) ^ swr]);
    *reinterpret_cast<bf16x8*>(O + (rowQ + row) * 1024 + hoff + c2 + i * 8) = ov;
  }
}

// --------------------------------- launch -------------------------------------------
extern "C" void kernel_launch(void* const* d_in, const int* in_sizes, int n_in,
                              void* d_out, int out_size, void* d_ws, size_t ws_size,
                              hipStream_t stream) {
  const float* x     = (const float*)d_in[0];
  const float* ln1_g = (const float*)d_in[1];
  const float* ln1_b = (const float*)d_in[2];
  const float* wq    = (const float*)d_in[3];
  const float* wk    = (const float*)d_in[4];
  const float* wv    = (const float*)d_in[5];
  const float* wo    = (const float*)d_in[6];
  const float* ln2_g = (const float*)d_in[7];
  const float* ln2_b = (const float*)d_in[8];
  const float* w1    = (const float*)d_in[9];
  const float* b1    = (const float*)d_in[10];
  const float* w2    = (const float*)d_in[11];
  const float* b2    = (const float*)d_in[12];

  const size_t MB = 1ull << 20;
  char* ws = (char*)d_ws;
  bf16* wTqkv = (bf16*)(ws + 0 * MB);    // 6MB
  bf16* wTo   = (bf16*)(ws + 6 * MB);    // 2MB
  bf16* wT1   = (bf16*)(ws + 8 * MB);    // 8MB
  bf16* wT2   = (bf16*)(ws + 16 * MB);   // 8MB
  bf16* x1    = (bf16*)(ws + 24 * MB);   // 8MB; attn out aliases; FFN2 p0 later
  bf16* qkv   = (bf16*)(ws + 32 * MB);   // 24MB; x2 / FFN2 p1-p3 alias
  bf16* xres  = (bf16*)(ws + 56 * MB);   // 8MB bf16 trunk
  bf16* h1    = (bf16*)(ws + 72 * MB);   // 32MB
  bf16* attn  = x1;
  bf16* x2    = qkv;
  bf16* pOp   = (bf16*)(ws + 40 * MB);   // o-proj partials: 2 x 8MB at [40,56)
  bf16* pF    = (bf16*)(ws + 24 * MB);   // FFN2 partials: 4 x 8MB at [24,56)

  const dim3 TB(256);

  // prologue: LN1 + qkv/o weight transposes (w1/w2 ride inside the QKV GEMM)
  prep_kernel<<<5120, TB, 0, stream>>>(wq, wk, wv, wo, wTqkv, wTo,
                                       x, ln1_g, ln1_b, x1);

  // fused QKV projection (192 GEMM blocks) + depth-3 w1/w2 transposes (64 aux)
  gemm256<0><<<256, dim3(512), 0, stream>>>(x1, wTqkv, qkv, nullptr,
                                            4096, 3072, 1024, 12, 192, 1024, 192,
                                            w1, w2, wT1, wT2);

  // attention: 512 blocks x 512 threads (8 waves x 16q)
  attn_kernel<<<512, dim3(512), 0, stream>>>(qkv, qkv + 1024, qkv + 2048, attn, 3072);

  // O projection: 128^2 2-phase split-K=2, grid 512 -> bf16 partials
  gemm_bt<3><<<512, TB, 0, stream>>>(attn, wTo, pOp, nullptr, 4096, 1024, 1024, 8, 256, 512);

  // fused: xres = bf16(p0+p1+x) ; x2 = LN2(fp32 sum)
  reduce_ln_kernel<<<1024, TB, 0, stream>>>(pOp, pOp + 4096 * 1024, x, ln2_g, ln2_b, xres, x2);

  // FFN1: relu(x2 @ w1 + b1) -> bf16; 256^2 8-phase, grid 256
  gemm256<2><<<256, dim3(512), 0, stream>>>(x2, wT1, h1, b1,
                                            4096, 4096, 1024, 16, 256, 1024, 256,
                                            nullptr, nullptr, nullptr, nullptr);

  // FFN2 split-K=4: 256^2 8-phase, grid 256 -> bf16 partials
  gemm256<3><<<256, dim3(512), 0, stream>>>(h1, wT2, pF, nullptr,
                                            4096, 1024, 4096, 4, 64, 1024, 256,
                                            nullptr, nullptr, nullptr, nullptr);

  // final: out = p0+p1+p2+p3 + b2 + xres
  reduce_out_kernel<<<2048, TB, 0, stream>>>(pF, pF + 4096 * 1024, pF + 2 * 4096 * 1024,
                                             pF + 3 * 4096 * 1024, b2, xres, (float*)d_out);
}

// Round 16
// 188.669 us; speedup vs baseline: 1.0150x; 1.0150x over previous
//
#include <hip/hip_runtime.h>

typedef __bf16 bf16;
typedef __bf16 bf16x8 __attribute__((ext_vector_type(8)));
typedef __bf16 bf16x4 __attribute__((ext_vector_type(4)));
typedef float f32x4 __attribute__((ext_vector_type(4)));

__device__ __forceinline__ void gload_lds16(const void* g, void* l) {
  __builtin_amdgcn_global_load_lds(
      (const __attribute__((address_space(1))) unsigned int*)g,
      (__attribute__((address_space(3))) unsigned int*)l, 16, 0, 0);
}

// ---- prologue: LN1 + wq/wk/wv/wo transposes (w1/w2 ride inside the QKV GEMM) -------
__global__ __launch_bounds__(256) void prep_kernel(
    const float* __restrict__ wq, const float* __restrict__ wk,
    const float* __restrict__ wv, const float* __restrict__ wo,
    bf16* __restrict__ wTqkv, bf16* __restrict__ wTo,
    const float* __restrict__ x, const float* __restrict__ g,
    const float* __restrict__ b, bf16* __restrict__ y) {
  const int id = blockIdx.x;
  if (id < 1024) {  // ---- LN1 ----
    const int w = threadIdx.x >> 6, lane = threadIdx.x & 63;
    const int row = id * 4 + w;
    const float* xr = x + (size_t)row * 1024;
    float4 v[4];
    float s = 0.f, sq = 0.f;
#pragma unroll
    for (int c = 0; c < 4; c++) {
      v[c] = *reinterpret_cast<const float4*>(xr + c * 256 + lane * 4);
      s += v[c].x + v[c].y + v[c].z + v[c].w;
      sq += v[c].x * v[c].x + v[c].y * v[c].y + v[c].z * v[c].z + v[c].w * v[c].w;
    }
#pragma unroll
    for (int d = 32; d >= 1; d >>= 1) {
      s += __shfl_xor(s, d, 64);
      sq += __shfl_xor(sq, d, 64);
    }
    const float mu = s * (1.f / 1024.f);
    const float rs = rsqrtf(sq * (1.f / 1024.f) - mu * mu + 1e-6f);
#pragma unroll
    for (int c = 0; c < 4; c++) {
      float4 gv = *reinterpret_cast<const float4*>(g + c * 256 + lane * 4);
      float4 bv = *reinterpret_cast<const float4*>(b + c * 256 + lane * 4);
      bf16x4 ov;
      ov[0] = (bf16)((v[c].x - mu) * rs * gv.x + bv.x);
      ov[1] = (bf16)((v[c].y - mu) * rs * gv.y + bv.y);
      ov[2] = (bf16)((v[c].z - mu) * rs * gv.z + bv.z);
      ov[3] = (bf16)((v[c].w - mu) * rs * gv.w + bv.w);
      *reinterpret_cast<bf16x4*>(y + (size_t)row * 1024 + c * 256 + lane * 4) = ov;
    }
    return;
  }
  __shared__ float tile[32][33];
  const int idx = id - 1024;
  const int m = idx >> 10, r = idx & 1023;
  const float* src = m == 0 ? wq : m == 1 ? wk : m == 2 ? wv : wo;
  bf16* dst = m == 3 ? wTo : wTqkv + (size_t)m * 1024 * 1024;
  const int tx = threadIdx.x & 31, ty = threadIdx.x >> 5;
  const int c0 = (r & 31) * 32, r0 = (r >> 5) * 32;
#pragma unroll
  for (int i = 0; i < 4; i++)
    tile[ty + i * 8][tx] = src[(size_t)(r0 + ty + i * 8) * 1024 + c0 + tx];
  __syncthreads();
#pragma unroll
  for (int i = 0; i < 4; i++)
    dst[(size_t)(c0 + ty + i * 8) * 1024 + r0 + tx] = (bf16)tile[tx][ty + i * 8];
}

// ---- fused reduce (o-proj split-K=2 partials) + residual + LayerNorm -----------------
__global__ __launch_bounds__(256) void reduce_ln_kernel(const bf16* __restrict__ p0,
                                                        const bf16* __restrict__ p1,
                                                        const float* __restrict__ x,
                                                        const float* __restrict__ g,
                                                        const float* __restrict__ b,
                                                        bf16* __restrict__ xres,
                                                        bf16* __restrict__ y) {
  const int w = threadIdx.x >> 6, lane = threadIdx.x & 63;
  const int row = blockIdx.x * 4 + w;
  const size_t rb = (size_t)row * 1024;
  float4 v[4];
  float s = 0.f, sq = 0.f;
#pragma unroll
  for (int c = 0; c < 4; c++) {
    const int off = c * 256 + lane * 4;
    float4 xv = *reinterpret_cast<const float4*>(x + rb + off);
    bf16x4 a0 = *reinterpret_cast<const bf16x4*>(p0 + rb + off);
    bf16x4 a1 = *reinterpret_cast<const bf16x4*>(p1 + rb + off);
    v[c].x = xv.x + (float)a0[0] + (float)a1[0];
    v[c].y = xv.y + (float)a0[1] + (float)a1[1];
    v[c].z = xv.z + (float)a0[2] + (float)a1[2];
    v[c].w = xv.w + (float)a0[3] + (float)a1[3];
    bf16x4 xo;
    xo[0] = (bf16)v[c].x; xo[1] = (bf16)v[c].y;
    xo[2] = (bf16)v[c].z; xo[3] = (bf16)v[c].w;
    *reinterpret_cast<bf16x4*>(xres + rb + off) = xo;
    s += v[c].x + v[c].y + v[c].z + v[c].w;
    sq += v[c].x * v[c].x + v[c].y * v[c].y + v[c].z * v[c].z + v[c].w * v[c].w;
  }
#pragma unroll
  for (int d = 32; d >= 1; d >>= 1) {
    s += __shfl_xor(s, d, 64);
    sq += __shfl_xor(sq, d, 64);
  }
  const float mu = s * (1.f / 1024.f);
  const float rs = rsqrtf(sq * (1.f / 1024.f) - mu * mu + 1e-6f);
#pragma unroll
  for (int c = 0; c < 4; c++) {
    const int off = c * 256 + lane * 4;
    float4 gv = *reinterpret_cast<const float4*>(g + off);
    float4 bv = *reinterpret_cast<const float4*>(b + off);
    bf16x4 ov;
    ov[0] = (bf16)((v[c].x - mu) * rs * gv.x + bv.x);
    ov[1] = (bf16)((v[c].y - mu) * rs * gv.y + bv.y);
    ov[2] = (bf16)((v[c].z - mu) * rs * gv.z + bv.z);
    ov[3] = (bf16)((v[c].w - mu) * rs * gv.w + bv.w);
    *reinterpret_cast<bf16x4*>(y + rb + off) = ov;
  }
}

// ---- final reduce (FFN2 split-K partials) + bias + bf16 residual -> fp32 out ---------
__global__ __launch_bounds__(256) void reduce_out_kernel(const bf16* __restrict__ p0,
                                                         const bf16* __restrict__ p1,
                                                         const bf16* __restrict__ p2,
                                                         const bf16* __restrict__ p3,
                                                         const float* __restrict__ bias,
                                                         const bf16* __restrict__ xres,
                                                         float* __restrict__ out) {
  const size_t i = ((size_t)blockIdx.x * 256 + threadIdx.x) * 8;
  const int col = (int)(i & 1023);
  bf16x8 a0 = *reinterpret_cast<const bf16x8*>(p0 + i);
  bf16x8 a1 = *reinterpret_cast<const bf16x8*>(p1 + i);
  bf16x8 a2 = *reinterpret_cast<const bf16x8*>(p2 + i);
  bf16x8 a3 = *reinterpret_cast<const bf16x8*>(p3 + i);
  bf16x8 xr = *reinterpret_cast<const bf16x8*>(xres + i);
  float4 b0 = *reinterpret_cast<const float4*>(bias + col);
  float4 b1 = *reinterpret_cast<const float4*>(bias + col + 4);
  float4 o0, o1;
  o0.x = (float)xr[0] + b0.x + (float)a0[0] + (float)a1[0] + (float)a2[0] + (float)a3[0];
  o0.y = (float)xr[1] + b0.y + (float)a0[1] + (float)a1[1] + (float)a2[1] + (float)a3[1];
  o0.z = (float)xr[2] + b0.z + (float)a0[2] + (float)a1[2] + (float)a2[2] + (float)a3[2];
  o0.w = (float)xr[3] + b0.w + (float)a0[3] + (float)a1[3] + (float)a2[3] + (float)a3[3];
  o1.x = (float)xr[4] + b1.x + (float)a0[4] + (float)a1[4] + (float)a2[4] + (float)a3[4];
  o1.y = (float)xr[5] + b1.y + (float)a0[5] + (float)a1[5] + (float)a2[5] + (float)a3[5];
  o1.z = (float)xr[6] + b1.z + (float)a0[6] + (float)a1[6] + (float)a2[6] + (float)a3[6];
  o1.w = (float)xr[7] + b1.w + (float)a0[7] + (float)a1[7] + (float)a2[7] + (float)a3[7];
  *reinterpret_cast<float4*>(out + i) = o0;
  *reinterpret_cast<float4*>(out + i + 4) = o1;
}

// ---------------- 128^2 GEMM (2-phase) for o-proj (split-K, bf16 partials) ------------
template <int EPI>
__global__ __launch_bounds__(256) void gemm_bt(const bf16* __restrict__ A,
                                               const bf16* __restrict__ Bt,
                                               void* __restrict__ Cout,
                                               const float* __restrict__ bias,
                                               int M, int N, int K, int gy, int gxy,
                                               int Kc) {
  __shared__ __align__(16) bf16 As[2][128][32];
  __shared__ __align__(16) bf16 Bs[2][128][32];
  const int tid = threadIdx.x;
  const int w = tid >> 6, lane = tid & 63;
  const int wr = w >> 1, wc = w & 1;

  const int nwg = gridDim.x;
  const int cpx = nwg >> 3;
  const int swz = (blockIdx.x & 7) * cpx + (blockIdx.x >> 3);
  const int chunk = swz / gxy, rem = swz % gxy;
  const int gpc = gy << 3;
  const int band = rem / gpc, r2 = rem % gpc;
  const int bm = (band * 8 + (r2 & 7)) * 128;
  const int bn = (r2 >> 3) * 128;

  f32x4 acc[4][4] = {};
  const int r4 = lane >> 2;
  const int c8 = (lane & 3) * 8;
  const bf16* Ag = A + (size_t)(bm + w * 32 + r4) * K + chunk * Kc + c8;
  const bf16* Bg = Bt + (size_t)(bn + w * 32 + r4) * K + chunk * Kc + c8;
  const int fr = lane & 15, fo = (lane >> 4) * 8;

#define STAGE(buf, k0)                                                 \
  do {                                                                 \
    gload_lds16(Ag + (k0), &As[buf][w * 32][0]);                       \
    gload_lds16(Ag + (size_t)16 * K + (k0), &As[buf][w * 32 + 16][0]); \
    gload_lds16(Bg + (k0), &Bs[buf][w * 32][0]);                       \
    gload_lds16(Bg + (size_t)16 * K + (k0), &Bs[buf][w * 32 + 16][0]); \
  } while (0)

  const int nt = Kc >> 5;
  STAGE(0, 0);
  __syncthreads();
  int cur = 0;
  for (int t = 0; t < nt; ++t) {
    if (t + 1 < nt) STAGE(cur ^ 1, (t + 1) << 5);
    bf16x8 af[4], bfr[4];
#pragma unroll
    for (int m = 0; m < 4; m++)
      af[m] = *reinterpret_cast<const bf16x8*>(&As[cur][wr * 64 + m * 16 + fr][fo]);
#pragma unroll
    for (int n = 0; n < 4; n++)
      bfr[n] = *reinterpret_cast<const bf16x8*>(&Bs[cur][wc * 64 + n * 16 + fr][fo]);
#pragma unroll
    for (int m = 0; m < 4; m++)
#pragma unroll
      for (int n = 0; n < 4; n++)
        acc[m][n] = __builtin_amdgcn_mfma_f32_16x16x32_bf16(af[m], bfr[n], acc[m][n], 0, 0, 0);
    __syncthreads();
    cur ^= 1;
  }
#undef STAGE

  bf16* outp = (bf16*)Cout + (EPI == 3 ? (size_t)chunk * M * N : 0);
  const int cr = (lane >> 4) * 4, cc = lane & 15;
#pragma unroll
  for (int m = 0; m < 4; m++) {
#pragma unroll
    for (int n = 0; n < 4; n++) {
      const int row = bm + wr * 64 + m * 16 + cr;
      const int col = bn + wc * 64 + n * 16 + cc;
#pragma unroll
      for (int r = 0; r < 4; r++) {
        const float va = acc[m][n][r];
        const size_t idx = (size_t)(row + r) * N + col;
        if (EPI == 0 || EPI == 3) {
          outp[idx] = (bf16)va;
        } else {
          const float t = va + bias[col];
          outp[idx] = (bf16)(t > 0.f ? t : 0.f);
        }
      }
    }
  }
}

// ---------------- 256^2 8-phase GEMM; naux>0: 8 aux blocks/XCD do strip transposes ----
template <int EPI>
__global__ __launch_bounds__(512, 2) void gemm256(const bf16* __restrict__ A,
                                                  const bf16* __restrict__ Bt,
                                                  void* __restrict__ Cout,
                                                  const float* __restrict__ bias,
                                                  int M, int N, int K, int gy, int gxy,
                                                  int Kc, int naux,
                                                  const float* __restrict__ tw1,
                                                  const float* __restrict__ tw2,
                                                  bf16* __restrict__ two1,
                                                  bf16* __restrict__ two2) {
  __shared__ __align__(16) bf16 As[2][256][64];
  __shared__ __align__(16) bf16 Bs[2][256][64];
  const int tid = threadIdx.x;
  const int w = tid >> 6, lane = tid & 63;
  const int wm = w >> 2, wn = w & 3;
  const int fr = lane & 15, g = lane >> 4;

  const int nwg = gridDim.x;
  const int cpx = nwg >> 3;
  const int swz = (blockIdx.x & 7) * cpx + (blockIdx.x >> 3);

  char* AsB = (char*)&As[0][0][0];
  char* BsB = (char*)&Bs[0][0][0];

  int gid = swz;
  if (naux > 0) {
    const int lid = swz & 31, xcd = swz >> 5;
    if (lid >= 24) {
      // ---- aux: 128x32 strip transposes, spread 8/XCD; float4 in, bf16x8 out ----
      const int aux = xcd * 8 + (lid - 24);  // 0..63
      const int t8 = tid & 255;
      const int sub = tid >> 8;  // 0..1
      float* tf = (float*)AsB + sub * (128 * 33);
      const int lrow = t8 >> 3;        // 0..31 (load row within 32-row group)
      const int lcol = (t8 & 7) * 4;   // float4 col
      const int drow = t8 >> 3;        // dst row within strip (0..31)
      const int dc = (t8 & 7) * 8;     // dst col base (0..56)

      const float* src; bf16* dst; int R, C, c0, r0;
#define SETJOB(job)                                                     \
      do {                                                              \
        if ((job) < 1024) {                                             \
          src = tw1; dst = two1; R = 1024; C = 4096;                    \
          r0 = ((job) >> 7) * 128; c0 = ((job) & 127) * 32;             \
        } else {                                                        \
          const int j2 = (job) - 1024;                                  \
          src = tw2; dst = two2; R = 4096; C = 1024;                    \
          r0 = (j2 >> 5) * 128; c0 = (j2 & 31) * 32;                    \
        }                                                               \
      } while (0)

      f32x4 cf[4], nf[4];
      SETJOB(aux * 2 + sub);
#pragma unroll
      for (int p = 0; p < 4; p++)
        cf[p] = *reinterpret_cast<const f32x4*>(
            &src[(size_t)(r0 + lrow + 32 * p) * C + c0 + lcol]);
      int c_0 = c0, r_0 = r0, R_0 = R;
      bf16* d_0 = dst;

      for (int t = 0; t < 16; ++t) {
        if (t + 1 < 16) {
          SETJOB((t + 1) * 128 + aux * 2 + sub);
#pragma unroll
          for (int p = 0; p < 4; p++)
            nf[p] = *reinterpret_cast<const f32x4*>(
                &src[(size_t)(r0 + lrow + 32 * p) * C + c0 + lcol]);
        }
#pragma unroll
        for (int p = 0; p < 4; p++)
#pragma unroll
          for (int j = 0; j < 4; j++)
            tf[(lrow + 32 * p) * 33 + lcol + j] = cf[p][j];
        __syncthreads();
        bf16x8 s0, s1;
#pragma unroll
        for (int k = 0; k < 8; k++) s0[k] = (bf16)tf[(dc + k) * 33 + drow];
#pragma unroll
        for (int k = 0; k < 8; k++) s1[k] = (bf16)tf[(64 + dc + k) * 33 + drow];
        *reinterpret_cast<bf16x8*>(&d_0[(size_t)(c_0 + drow) * R_0 + r_0 + dc]) = s0;
        *reinterpret_cast<bf16x8*>(&d_0[(size_t)(c_0 + drow) * R_0 + r_0 + 64 + dc]) = s1;
        __syncthreads();
#pragma unroll
        for (int p = 0; p < 4; p++) cf[p] = nf[p];
        c_0 = c0; r_0 = r0; R_0 = R; d_0 = dst;
      }
#undef SETJOB
      return;
    }
    gid = xcd * 24 + lid;  // 24 GEMM blocks per XCD -> 0..191
  }

  const int chunk = gid / gxy, rem = gid % gxy;
  const int gpc = gy << 3;
  const int band = rem / gpc, r2 = rem % gpc;
  const int bm = (band * 8 + (r2 & 7)) * 256;
  const int bn = (r2 >> 3) * 256;

  const bf16* Ab = A + (size_t)bm * K;
  const bf16* Bb = Bt + (size_t)bn * K;

  const int lr = lane >> 3;
  const int sle = ((lane & 7) ^ lr) * 8;
  const int rB0 = w * 16;
  const int rB1 = 128 + w * 16;
  const int rA0 = wm * 128 + wn * 16;
  const int rA1 = wm * 128 + 64 + wn * 16;

  const int rowA = (wm * 128 + fr) * 128;
  const int rowB = (wn * 64 + fr) * 128;
  const int colk0 = (g * 16) ^ ((fr & 7) << 4);
  const int colk1 = (64 + g * 16) ^ ((fr & 7) << 4);

  f32x4 acc[8][4] = {};

#define SG8(base, r0, kb, ldsrow)                                           \
  do {                                                                      \
    gload_lds16(base + (size_t)((r0) + lr) * K + (kb) + sle, (ldsrow));     \
    gload_lds16(base + (size_t)((r0) + 8 + lr) * K + (kb) + sle,            \
                (char*)(ldsrow) + 1024);                                    \
  } while (0)

  const int nt = Kc >> 6;
  const int koff = chunk * Kc;

  SG8(Bb, rB0, koff, BsB + rB0 * 128);
  SG8(Bb, rB1, koff, BsB + rB1 * 128);
  SG8(Ab, rA0, koff, AsB + rA0 * 128);
  SG8(Ab, rA1, koff, AsB + rA1 * 128);

#define PHASE_BODY(p, mb)                                                     \
  {                                                                           \
    if ((p) == 0) {                                                           \
      _Pragma("unroll") for (int nf = 0; nf < 4; nf++) {                      \
        bfr[nf][0] = *(const bf16x8*)(Br + rowB + nf * 2048 + colk0);         \
        bfr[nf][1] = *(const bf16x8*)(Br + rowB + nf * 2048 + colk1);         \
      }                                                                       \
    }                                                                         \
    af[0][0] = *(const bf16x8*)(Ar + rowA + (mb)*2048 + colk0);               \
    af[0][1] = *(const bf16x8*)(Ar + rowA + (mb)*2048 + colk1);               \
    af[1][0] = *(const bf16x8*)(Ar + rowA + ((mb) + 1) * 2048 + colk0);       \
    af[1][1] = *(const bf16x8*)(Ar + rowA + ((mb) + 1) * 2048 + colk1);       \
    if (pre) {                                                                \
      if ((p) == 0) SG8(Bb, rB0, kb2, Bw + rB0 * 128);                        \
      if ((p) == 1) SG8(Bb, rB1, kb2, Bw + rB1 * 128);                        \
      if ((p) == 2) SG8(Ab, rA0, kb2, Aw + rA0 * 128);                        \
      if ((p) == 3) SG8(Ab, rA1, kb2, Aw + rA1 * 128);                        \
    }                                                                         \
    __builtin_amdgcn_s_setprio(1);                                            \
    _Pragma("unroll") for (int m2 = 0; m2 < 2; m2++)                          \
        _Pragma("unroll") for (int nf = 0; nf < 4; nf++) {                    \
      acc[(mb) + m2][nf] = __builtin_amdgcn_mfma_f32_16x16x32_bf16(           \
          af[m2][0], bfr[nf][0], acc[(mb) + m2][nf], 0, 0, 0);                \
      acc[(mb) + m2][nf] = __builtin_amdgcn_mfma_f32_16x16x32_bf16(           \
          af[m2][1], bfr[nf][1], acc[(mb) + m2][nf], 0, 0, 0);                \
    }                                                                         \
    __builtin_amdgcn_s_setprio(0);                                            \
  }

  int buf = 0;
  for (int kt = 0; kt < nt; ++kt) {
    char* Ar = AsB + buf * 32768;
    char* Br = BsB + buf * 32768;
    char* Aw = AsB + (buf ^ 1) * 32768;
    char* Bw = BsB + (buf ^ 1) * 32768;
    const bool pre = (kt + 1) < nt;
    const int kb2 = koff + (kt + 1) * 64;
    bf16x8 bfr[4][2];
    bf16x8 af[2][2];

    asm volatile("s_waitcnt vmcnt(2)" ::: "memory");
    __builtin_amdgcn_s_barrier();
    PHASE_BODY(0, 0)

    if (pre) asm volatile("s_waitcnt vmcnt(4)" ::: "memory");
    else     asm volatile("s_waitcnt vmcnt(2)" ::: "memory");
    __builtin_amdgcn_s_barrier();
    PHASE_BODY(1, 2)

    if (pre) asm volatile("s_waitcnt vmcnt(4)" ::: "memory");
    else     asm volatile("s_waitcnt vmcnt(0)" ::: "memory");
    __builtin_amdgcn_s_barrier();
    PHASE_BODY(2, 4)

    if (pre) asm volatile("s_waitcnt vmcnt(6)" ::: "memory");
    else     asm volatile("s_waitcnt vmcnt(0)" ::: "memory");
    __builtin_amdgcn_s_barrier();
    PHASE_BODY(3, 6)

    buf ^= 1;
  }
#undef PHASE_BODY
#undef SG8

  bf16* outp = (bf16*)Cout + (EPI == 3 ? (size_t)chunk * M * N : 0);
  const int cr = g * 4;
#pragma unroll
  for (int mf = 0; mf < 8; mf++) {
#pragma unroll
    for (int nf = 0; nf < 4; nf++) {
      const int row = bm + wm * 128 + mf * 16 + cr;
      const int col = bn + wn * 64 + nf * 16 + fr;
#pragma unroll
      for (int r = 0; r < 4; r++) {
        const float va = acc[mf][nf][r];
        const size_t idx = (size_t)(row + r) * N + col;
        if (EPI == 3 || EPI == 0) {
          outp[idx] = (bf16)va;
        } else {
          const float t = va + bias[col];
          outp[idx] = (bf16)(t > 0.f ? t : 0.f);
        }
      }
    }
  }
}

// ---------------- Flash attention v4: 8 waves x 16q, no-max softmax, unroll x2 --------
__global__ __launch_bounds__(512, 4) void attn_kernel(const bf16* __restrict__ Q,
                                                      const bf16* __restrict__ K,
                                                      const bf16* __restrict__ V,
                                                      bf16* __restrict__ O, int ld) {
  __shared__ __align__(16) bf16 Ks[2][64][64];
  __shared__ __align__(16) bf16 Vt[2][64][64];
  __shared__ __align__(16) bf16 Pl[8][16][64];
  const int tid = threadIdx.x;
  const int w = tid >> 6, l = tid & 63;
  const int lo = l & 15, g = l >> 4;
  const int sw = (lo & 7) << 3;

  const int id = blockIdx.x;
  const int bh = id & 63, qb = id >> 6;
  const int b = bh >> 4, h = bh & 15;
  const int hoff = h * 64;
  const size_t rowQ = (size_t)b * 1024 + qb * 128 + w * 16;
  const size_t rowKV0 = (size_t)b * 1024;

  const int srow = tid >> 3, scch = tid & 7;
  const int vcb = w * 8;

  bf16x8 qfr[2];
#pragma unroll
  for (int ds = 0; ds < 2; ds++)
    qfr[ds] = *reinterpret_cast<const bf16x8*>(
        Q + (rowQ + lo) * ld + hoff + ds * 32 + g * 8);

  const float c = 0.18033688f;  // 0.125 * log2(e)
  f32x4 lacc = {0.f, 0.f, 0.f, 0.f};
  f32x4 o[4] = {};

  {
    gload_lds16(K + (rowKV0 + srow) * ld + hoff + ((scch ^ (srow & 7)) << 3),
                &Ks[0][w * 8][0]);
    bf16x8 vv = *reinterpret_cast<const bf16x8*>(V + (rowKV0 + l) * ld + hoff + vcb);
#pragma unroll
    for (int j = 0; j < 8; j++) Vt[0][vcb + j][l ^ (j << 3)] = vv[j];
  }
  __syncthreads();

#define ATILE(PAR, KT)                                                               \
  {                                                                                  \
    bf16x8 vv;                                                                       \
    const bool more = (KT) + 1 < 16;                                                 \
    if (more) {                                                                      \
      const size_t rkv = rowKV0 + ((KT) + 1) * 64;                                   \
      gload_lds16(K + (rkv + srow) * ld + hoff + ((scch ^ (srow & 7)) << 3),         \
                  &Ks[(PAR) ^ 1][w * 8][0]);                                         \
      vv = *reinterpret_cast<const bf16x8*>(V + (rkv + l) * ld + hoff + vcb);        \
    }                                                                                \
    f32x4 sa[4] = {};                                                                \
    _Pragma("unroll") for (int ds = 0; ds < 2; ds++) {                               \
      bf16x8 kf[4];                                                                  \
      _Pragma("unroll") for (int kfi = 0; kfi < 4; kfi++)                            \
          kf[kfi] = *reinterpret_cast<const bf16x8*>(                                \
              &Ks[PAR][kfi * 16 + lo][(ds * 32 + g * 8) ^ sw]);                      \
      _Pragma("unroll") for (int kfi = 0; kfi < 4; kfi++)                            \
          sa[kfi] =                                                                  \
              __builtin_amdgcn_mfma_f32_16x16x32_bf16(kf[kfi], qfr[ds], sa[kfi], 0, 0, 0); \
    }                                                                                \
    float p[16];                                                                     \
    _Pragma("unroll") for (int kfi = 0; kfi < 4; kfi++)                              \
        _Pragma("unroll") for (int r = 0; r < 4; r++)                                \
            p[kfi * 4 + r] = exp2f(sa[kfi][r] * c);                                  \
    _Pragma("unroll") for (int r = 0; r < 4; r++)                                    \
        lacc[r] += (p[r] + p[4 + r]) + (p[8 + r] + p[12 + r]);                       \
    _Pragma("unroll") for (int kfi = 0; kfi < 4; kfi++) {                            \
      bf16x4 pk;                                                                     \
      pk[0] = (bf16)p[kfi * 4 + 0];                                                  \
      pk[1] = (bf16)p[kfi * 4 + 1];                                                  \
      pk[2] = (bf16)p[kfi * 4 + 2];                                                  \
      pk[3] = (bf16)p[kfi * 4 + 3];                                                  \
      *reinterpret_cast<bf16x4*>(&Pl[w][lo][(kfi * 16 + g * 4) ^ sw]) = pk;          \
    }                                                                                \
    _Pragma("unroll") for (int ks = 0; ks < 2; ks++) {                               \
      bf16x8 pf = *reinterpret_cast<const bf16x8*>(&Pl[w][lo][(ks * 32 + g * 8) ^ sw]); \
      _Pragma("unroll") for (int df = 0; df < 4; df++) {                             \
        bf16x8 vf = *reinterpret_cast<const bf16x8*>(                                \
            &Vt[PAR][df * 16 + lo][(ks * 32 + g * 8) ^ sw]);                         \
        o[df] = __builtin_amdgcn_mfma_f32_16x16x32_bf16(vf, pf, o[df], 0, 0, 0);     \
      }                                                                              \
    }                                                                                \
    if (more) {                                                                      \
      _Pragma("unroll") for (int j = 0; j < 8; j++)                                  \
          Vt[(PAR) ^ 1][vcb + j][l ^ (j << 3)] = vv[j];                              \
    }                                                                                \
    __syncthreads();                                                                 \
  }

  for (int kt2 = 0; kt2 < 16; kt2 += 2) {
    ATILE(0, kt2)
    ATILE(1, kt2 + 1)
  }
#undef ATILE

  float lsum = (lacc[0] + lacc[1]) + (lacc[2] + lacc[3]);
  lsum += __shfl_xor(lsum, 16);
  lsum += __shfl_xor(lsum, 32);
  const float rl = 1.f / lsum;
#pragma unroll
  for (int df = 0; df < 4; df++) {
    bf16x4 ov;
#pragma unroll
    for (int r = 0; r < 4; r++) ov[r] = (bf16)(o[df][r] * rl);
    *reinterpret_cast<bf16x4*>(&Pl[w][lo][(df * 16 + g * 4) ^ sw]) = ov;
  }
  const int row = l >> 2;
  const int swr = (row & 7) << 3;
  const int c2 = (l & 3) * 16;
#pragma unroll
  for (int i = 0; i < 2; i++) {
    bf16x8 ov = *reinterpret_cast<const bf16x8*>(&Pl[w][row][(c2 + i * 8) ^ swr]);
    *reinterpret_cast<bf16x8*>(O + (rowQ + row) * 1024 + hoff + c2 + i * 8) = ov;
  }
}

// --------------------------------- launch -------------------------------------------
extern "C" void kernel_launch(void* const* d_in, const int* in_sizes, int n_in,
                              void* d_out, int out_size, void* d_ws, size_t ws_size,
                              hipStream_t stream) {
  const float* x     = (const float*)d_in[0];
  const float* ln1_g = (const float*)d_in[1];
  const float* ln1_b = (const float*)d_in[2];
  const float* wq    = (const float*)d_in[3];
  const float* wk    = (const float*)d_in[4];
  const float* wv    = (const float*)d_in[5];
  const float* wo    = (const float*)d_in[6];
  const float* ln2_g = (const float*)d_in[7];
  const float* ln2_b = (const float*)d_in[8];
  const float* w1    = (const float*)d_in[9];
  const float* b1    = (const float*)d_in[10];
  const float* w2    = (const float*)d_in[11];
  const float* b2    = (const float*)d_in[12];

  const size_t MB = 1ull << 20;
  char* ws = (char*)d_ws;
  bf16* wTqkv = (bf16*)(ws + 0 * MB);    // 6MB
  bf16* wTo   = (bf16*)(ws + 6 * MB);    // 2MB
  bf16* wT1   = (bf16*)(ws + 8 * MB);    // 8MB
  bf16* wT2   = (bf16*)(ws + 16 * MB);   // 8MB
  bf16* x1    = (bf16*)(ws + 24 * MB);   // 8MB; attn out aliases; FFN2 p0 later
  bf16* qkv   = (bf16*)(ws + 32 * MB);   // 24MB; x2 / FFN2 p1-p3 alias
  bf16* xres  = (bf16*)(ws + 56 * MB);   // 8MB bf16 trunk
  bf16* h1    = (bf16*)(ws + 72 * MB);   // 32MB
  bf16* attn  = x1;
  bf16* x2    = qkv;
  bf16* pOp   = (bf16*)(ws + 40 * MB);   // o-proj partials: 2 x 8MB at [40,56)
  bf16* pF    = (bf16*)(ws + 24 * MB);   // FFN2 partials: 4 x 8MB at [24,56)

  const dim3 TB(256);

  // prologue: LN1 + qkv/o weight transposes (w1/w2 ride inside the QKV GEMM)
  prep_kernel<<<5120, TB, 0, stream>>>(wq, wk, wv, wo, wTqkv, wTo,
                                       x, ln1_g, ln1_b, x1);

  // fused QKV projection (24 GEMM + 8 aux blocks per XCD)
  gemm256<0><<<256, dim3(512), 0, stream>>>(x1, wTqkv, qkv, nullptr,
                                            4096, 3072, 1024, 12, 192, 1024, 64,
                                            w1, w2, wT1, wT2);

  // attention: 512 blocks x 512 threads (8 waves x 16q)
  attn_kernel<<<512, dim3(512), 0, stream>>>(qkv, qkv + 1024, qkv + 2048, attn, 3072);

  // O projection: 128^2 2-phase split-K=2, grid 512 -> bf16 partials
  gemm_bt<3><<<512, TB, 0, stream>>>(attn, wTo, pOp, nullptr, 4096, 1024, 1024, 8, 256, 512);

  // fused: xres = bf16(p0+p1+x) ; x2 = LN2(fp32 sum)
  reduce_ln_kernel<<<1024, TB, 0, stream>>>(pOp, pOp + 4096 * 1024, x, ln2_g, ln2_b, xres, x2);

  // FFN1: relu(x2 @ w1 + b1) -> bf16; 256^2 8-phase, grid 256
  gemm256<2><<<256, dim3(512), 0, stream>>>(x2, wT1, h1, b1,
                                            4096, 4096, 1024, 16, 256, 1024, 0,
                                            nullptr, nullptr, nullptr, nullptr);

  // FFN2 split-K=4: 256^2 8-phase, grid 256 -> bf16 partials
  gemm256<3><<<256, dim3(512), 0, stream>>>(h1, wT2, pF, nullptr,
                                            4096, 1024, 4096, 4, 64, 1024, 0,
                                            nullptr, nullptr, nullptr, nullptr);

  // final: out = p0+p1+p2+p3 + b2 + xres
  reduce_out_kernel<<<2048, TB, 0, stream>>>(pF, pF + 4096 * 1024, pF + 2 * 4096 * 1024,
                                             pF + 3 * 4096 * 1024, b2, xres, (float*)d_out);
}

// Round 17
// 188.167 us; speedup vs baseline: 1.0177x; 1.0027x over previous
//
#include <hip/hip_runtime.h>

typedef __bf16 bf16;
typedef __bf16 bf16x8 __attribute__((ext_vector_type(8)));
typedef __bf16 bf16x4 __attribute__((ext_vector_type(4)));
typedef float f32x4 __attribute__((ext_vector_type(4)));

__device__ __forceinline__ void gload_lds16(const void* g, void* l) {
  __builtin_amdgcn_global_load_lds(
      (const __attribute__((address_space(1))) unsigned int*)g,
      (__attribute__((address_space(3))) unsigned int*)l, 16, 0, 0);
}

// ---- prologue: LN1 + wq/wk/wv/wo transposes (w1/w2 ride inside the QKV GEMM) -------
__global__ __launch_bounds__(256) void prep_kernel(
    const float* __restrict__ wq, const float* __restrict__ wk,
    const float* __restrict__ wv, const float* __restrict__ wo,
    bf16* __restrict__ wTqkv, bf16* __restrict__ wTo,
    const float* __restrict__ x, const float* __restrict__ g,
    const float* __restrict__ b, bf16* __restrict__ y) {
  const int id = blockIdx.x;
  if (id < 1024) {  // ---- LN1 ----
    const int w = threadIdx.x >> 6, lane = threadIdx.x & 63;
    const int row = id * 4 + w;
    const float* xr = x + (size_t)row * 1024;
    float4 v[4];
    float s = 0.f, sq = 0.f;
#pragma unroll
    for (int c = 0; c < 4; c++) {
      v[c] = *reinterpret_cast<const float4*>(xr + c * 256 + lane * 4);
      s += v[c].x + v[c].y + v[c].z + v[c].w;
      sq += v[c].x * v[c].x + v[c].y * v[c].y + v[c].z * v[c].z + v[c].w * v[c].w;
    }
#pragma unroll
    for (int d = 32; d >= 1; d >>= 1) {
      s += __shfl_xor(s, d, 64);
      sq += __shfl_xor(sq, d, 64);
    }
    const float mu = s * (1.f / 1024.f);
    const float rs = rsqrtf(sq * (1.f / 1024.f) - mu * mu + 1e-6f);
#pragma unroll
    for (int c = 0; c < 4; c++) {
      float4 gv = *reinterpret_cast<const float4*>(g + c * 256 + lane * 4);
      float4 bv = *reinterpret_cast<const float4*>(b + c * 256 + lane * 4);
      bf16x4 ov;
      ov[0] = (bf16)((v[c].x - mu) * rs * gv.x + bv.x);
      ov[1] = (bf16)((v[c].y - mu) * rs * gv.y + bv.y);
      ov[2] = (bf16)((v[c].z - mu) * rs * gv.z + bv.z);
      ov[3] = (bf16)((v[c].w - mu) * rs * gv.w + bv.w);
      *reinterpret_cast<bf16x4*>(y + (size_t)row * 1024 + c * 256 + lane * 4) = ov;
    }
    return;
  }
  __shared__ float tile[32][33];
  const int idx = id - 1024;
  const int m = idx >> 10, r = idx & 1023;
  const float* src = m == 0 ? wq : m == 1 ? wk : m == 2 ? wv : wo;
  bf16* dst = m == 3 ? wTo : wTqkv + (size_t)m * 1024 * 1024;
  const int tx = threadIdx.x & 31, ty = threadIdx.x >> 5;
  const int c0 = (r & 31) * 32, r0 = (r >> 5) * 32;
#pragma unroll
  for (int i = 0; i < 4; i++)
    tile[ty + i * 8][tx] = src[(size_t)(r0 + ty + i * 8) * 1024 + c0 + tx];
  __syncthreads();
#pragma unroll
  for (int i = 0; i < 4; i++)
    dst[(size_t)(c0 + ty + i * 8) * 1024 + r0 + tx] = (bf16)tile[tx][ty + i * 8];
}

// ---- fused reduce (o-proj split-K=2 partials) + residual + LayerNorm -----------------
__global__ __launch_bounds__(256) void reduce_ln_kernel(const bf16* __restrict__ p0,
                                                        const bf16* __restrict__ p1,
                                                        const float* __restrict__ x,
                                                        const float* __restrict__ g,
                                                        const float* __restrict__ b,
                                                        bf16* __restrict__ xres,
                                                        bf16* __restrict__ y) {
  const int w = threadIdx.x >> 6, lane = threadIdx.x & 63;
  const int row = blockIdx.x * 4 + w;
  const size_t rb = (size_t)row * 1024;
  float4 v[4];
  float s = 0.f, sq = 0.f;
#pragma unroll
  for (int c = 0; c < 4; c++) {
    const int off = c * 256 + lane * 4;
    float4 xv = *reinterpret_cast<const float4*>(x + rb + off);
    bf16x4 a0 = *reinterpret_cast<const bf16x4*>(p0 + rb + off);
    bf16x4 a1 = *reinterpret_cast<const bf16x4*>(p1 + rb + off);
    v[c].x = xv.x + (float)a0[0] + (float)a1[0];
    v[c].y = xv.y + (float)a0[1] + (float)a1[1];
    v[c].z = xv.z + (float)a0[2] + (float)a1[2];
    v[c].w = xv.w + (float)a0[3] + (float)a1[3];
    bf16x4 xo;
    xo[0] = (bf16)v[c].x; xo[1] = (bf16)v[c].y;
    xo[2] = (bf16)v[c].z; xo[3] = (bf16)v[c].w;
    *reinterpret_cast<bf16x4*>(xres + rb + off) = xo;
    s += v[c].x + v[c].y + v[c].z + v[c].w;
    sq += v[c].x * v[c].x + v[c].y * v[c].y + v[c].z * v[c].z + v[c].w * v[c].w;
  }
#pragma unroll
  for (int d = 32; d >= 1; d >>= 1) {
    s += __shfl_xor(s, d, 64);
    sq += __shfl_xor(sq, d, 64);
  }
  const float mu = s * (1.f / 1024.f);
  const float rs = rsqrtf(sq * (1.f / 1024.f) - mu * mu + 1e-6f);
#pragma unroll
  for (int c = 0; c < 4; c++) {
    const int off = c * 256 + lane * 4;
    float4 gv = *reinterpret_cast<const float4*>(g + off);
    float4 bv = *reinterpret_cast<const float4*>(b + off);
    bf16x4 ov;
    ov[0] = (bf16)((v[c].x - mu) * rs * gv.x + bv.x);
    ov[1] = (bf16)((v[c].y - mu) * rs * gv.y + bv.y);
    ov[2] = (bf16)((v[c].z - mu) * rs * gv.z + bv.z);
    ov[3] = (bf16)((v[c].w - mu) * rs * gv.w + bv.w);
    *reinterpret_cast<bf16x4*>(y + rb + off) = ov;
  }
}

// ---- final reduce (FFN2 split-K partials) + bias + bf16 residual -> fp32 out ---------
__global__ __launch_bounds__(256) void reduce_out_kernel(const bf16* __restrict__ p0,
                                                         const bf16* __restrict__ p1,
                                                         const bf16* __restrict__ p2,
                                                         const bf16* __restrict__ p3,
                                                         const float* __restrict__ bias,
                                                         const bf16* __restrict__ xres,
                                                         float* __restrict__ out) {
  const size_t i = ((size_t)blockIdx.x * 256 + threadIdx.x) * 8;
  const int col = (int)(i & 1023);
  bf16x8 a0 = *reinterpret_cast<const bf16x8*>(p0 + i);
  bf16x8 a1 = *reinterpret_cast<const bf16x8*>(p1 + i);
  bf16x8 a2 = *reinterpret_cast<const bf16x8*>(p2 + i);
  bf16x8 a3 = *reinterpret_cast<const bf16x8*>(p3 + i);
  bf16x8 xr = *reinterpret_cast<const bf16x8*>(xres + i);
  float4 b0 = *reinterpret_cast<const float4*>(bias + col);
  float4 b1 = *reinterpret_cast<const float4*>(bias + col + 4);
  float4 o0, o1;
  o0.x = (float)xr[0] + b0.x + (float)a0[0] + (float)a1[0] + (float)a2[0] + (float)a3[0];
  o0.y = (float)xr[1] + b0.y + (float)a0[1] + (float)a1[1] + (float)a2[1] + (float)a3[1];
  o0.z = (float)xr[2] + b0.z + (float)a0[2] + (float)a1[2] + (float)a2[2] + (float)a3[2];
  o0.w = (float)xr[3] + b0.w + (float)a0[3] + (float)a1[3] + (float)a2[3] + (float)a3[3];
  o1.x = (float)xr[4] + b1.x + (float)a0[4] + (float)a1[4] + (float)a2[4] + (float)a3[4];
  o1.y = (float)xr[5] + b1.y + (float)a0[5] + (float)a1[5] + (float)a2[5] + (float)a3[5];
  o1.z = (float)xr[6] + b1.z + (float)a0[6] + (float)a1[6] + (float)a2[6] + (float)a3[6];
  o1.w = (float)xr[7] + b1.w + (float)a0[7] + (float)a1[7] + (float)a2[7] + (float)a3[7];
  *reinterpret_cast<float4*>(out + i) = o0;
  *reinterpret_cast<float4*>(out + i + 4) = o1;
}

// ---------------- 128^2 GEMM (2-phase) for o-proj (split-K, bf16 partials) ------------
template <int EPI>
__global__ __launch_bounds__(256) void gemm_bt(const bf16* __restrict__ A,
                                               const bf16* __restrict__ Bt,
                                               void* __restrict__ Cout,
                                               const float* __restrict__ bias,
                                               int M, int N, int K, int gy, int gxy,
                                               int Kc) {
  __shared__ __align__(16) bf16 As[2][128][32];
  __shared__ __align__(16) bf16 Bs[2][128][32];
  const int tid = threadIdx.x;
  const int w = tid >> 6, lane = tid & 63;
  const int wr = w >> 1, wc = w & 1;

  const int nwg = gridDim.x;
  const int cpx = nwg >> 3;
  const int swz = (blockIdx.x & 7) * cpx + (blockIdx.x >> 3);
  const int chunk = swz / gxy, rem = swz % gxy;
  const int gpc = gy << 3;
  const int band = rem / gpc, r2 = rem % gpc;
  const int bm = (band * 8 + (r2 & 7)) * 128;
  const int bn = (r2 >> 3) * 128;

  f32x4 acc[4][4] = {};
  const int r4 = lane >> 2;
  const int c8 = (lane & 3) * 8;
  const bf16* Ag = A + (size_t)(bm + w * 32 + r4) * K + chunk * Kc + c8;
  const bf16* Bg = Bt + (size_t)(bn + w * 32 + r4) * K + chunk * Kc + c8;
  const int fr = lane & 15, fo = (lane >> 4) * 8;

#define STAGE(buf, k0)                                                 \
  do {                                                                 \
    gload_lds16(Ag + (k0), &As[buf][w * 32][0]);                       \
    gload_lds16(Ag + (size_t)16 * K + (k0), &As[buf][w * 32 + 16][0]); \
    gload_lds16(Bg + (k0), &Bs[buf][w * 32][0]);                       \
    gload_lds16(Bg + (size_t)16 * K + (k0), &Bs[buf][w * 32 + 16][0]); \
  } while (0)

  const int nt = Kc >> 5;
  STAGE(0, 0);
  __syncthreads();
  int cur = 0;
  for (int t = 0; t < nt; ++t) {
    if (t + 1 < nt) STAGE(cur ^ 1, (t + 1) << 5);
    bf16x8 af[4], bfr[4];
#pragma unroll
    for (int m = 0; m < 4; m++)
      af[m] = *reinterpret_cast<const bf16x8*>(&As[cur][wr * 64 + m * 16 + fr][fo]);
#pragma unroll
    for (int n = 0; n < 4; n++)
      bfr[n] = *reinterpret_cast<const bf16x8*>(&Bs[cur][wc * 64 + n * 16 + fr][fo]);
#pragma unroll
    for (int m = 0; m < 4; m++)
#pragma unroll
      for (int n = 0; n < 4; n++)
        acc[m][n] = __builtin_amdgcn_mfma_f32_16x16x32_bf16(af[m], bfr[n], acc[m][n], 0, 0, 0);
    __syncthreads();
    cur ^= 1;
  }
#undef STAGE

  bf16* outp = (bf16*)Cout + (EPI == 3 ? (size_t)chunk * M * N : 0);
  const int cr = (lane >> 4) * 4, cc = lane & 15;
#pragma unroll
  for (int m = 0; m < 4; m++) {
#pragma unroll
    for (int n = 0; n < 4; n++) {
      const int row = bm + wr * 64 + m * 16 + cr;
      const int col = bn + wc * 64 + n * 16 + cc;
#pragma unroll
      for (int r = 0; r < 4; r++) {
        const float va = acc[m][n][r];
        const size_t idx = (size_t)(row + r) * N + col;
        if (EPI == 0 || EPI == 3) {
          outp[idx] = (bf16)va;
        } else {
          const float t = va + bias[col];
          outp[idx] = (bf16)(t > 0.f ? t : 0.f);
        }
      }
    }
  }
}

// ---------------- 256^2 8-phase GEMM; naux>0: 8 aux blocks/XCD do strip transposes ----
template <int EPI>
__global__ __launch_bounds__(512, 2) void gemm256(const bf16* __restrict__ A,
                                                  const bf16* __restrict__ Bt,
                                                  void* __restrict__ Cout,
                                                  const float* __restrict__ bias,
                                                  int M, int N, int K, int gy, int gxy,
                                                  int Kc, int naux,
                                                  const float* __restrict__ tw1,
                                                  const float* __restrict__ tw2,
                                                  bf16* __restrict__ two1,
                                                  bf16* __restrict__ two2) {
  __shared__ __align__(16) bf16 As[2][256][64];
  __shared__ __align__(16) bf16 Bs[2][256][64];
  const int tid = threadIdx.x;
  const int w = tid >> 6, lane = tid & 63;
  const int wm = w >> 2, wn = w & 3;
  const int fr = lane & 15, g = lane >> 4;

  const int nwg = gridDim.x;
  const int cpx = nwg >> 3;
  const int swz = (blockIdx.x & 7) * cpx + (blockIdx.x >> 3);

  char* AsB = (char*)&As[0][0][0];
  char* BsB = (char*)&Bs[0][0][0];

  int gid = swz;
  if (naux > 0) {
    const int lid = swz & 31, xcd = swz >> 5;
    if (lid >= 24) {
      const int aux = xcd * 8 + (lid - 24);  // 0..63
      const int t8 = tid & 255;
      const int sub = tid >> 8;
      float* tf = (float*)AsB + sub * (128 * 33);
      const int lrow = t8 >> 3;
      const int lcol = (t8 & 7) * 4;
      const int drow = t8 >> 3;
      const int dc = (t8 & 7) * 8;

      const float* src; bf16* dst; int R, C, c0, r0;
#define SETJOB(job)                                                     \
      do {                                                              \
        if ((job) < 1024) {                                             \
          src = tw1; dst = two1; R = 1024; C = 4096;                    \
          r0 = ((job) >> 7) * 128; c0 = ((job) & 127) * 32;             \
        } else {                                                        \
          const int j2 = (job) - 1024;                                  \
          src = tw2; dst = two2; R = 4096; C = 1024;                    \
          r0 = (j2 >> 5) * 128; c0 = (j2 & 31) * 32;                    \
        }                                                               \
      } while (0)

      f32x4 cf[4], nf[4];
      SETJOB(aux * 2 + sub);
#pragma unroll
      for (int p = 0; p < 4; p++)
        cf[p] = *reinterpret_cast<const f32x4*>(
            &src[(size_t)(r0 + lrow + 32 * p) * C + c0 + lcol]);
      int c_0 = c0, r_0 = r0, R_0 = R;
      bf16* d_0 = dst;

      for (int t = 0; t < 16; ++t) {
        if (t + 1 < 16) {
          SETJOB((t + 1) * 128 + aux * 2 + sub);
#pragma unroll
          for (int p = 0; p < 4; p++)
            nf[p] = *reinterpret_cast<const f32x4*>(
                &src[(size_t)(r0 + lrow + 32 * p) * C + c0 + lcol]);
        }
#pragma unroll
        for (int p = 0; p < 4; p++)
#pragma unroll
          for (int j = 0; j < 4; j++)
            tf[(lrow + 32 * p) * 33 + lcol + j] = cf[p][j];
        __syncthreads();
        bf16x8 s0, s1;
#pragma unroll
        for (int k = 0; k < 8; k++) s0[k] = (bf16)tf[(dc + k) * 33 + drow];
#pragma unroll
        for (int k = 0; k < 8; k++) s1[k] = (bf16)tf[(64 + dc + k) * 33 + drow];
        *reinterpret_cast<bf16x8*>(&d_0[(size_t)(c_0 + drow) * R_0 + r_0 + dc]) = s0;
        *reinterpret_cast<bf16x8*>(&d_0[(size_t)(c_0 + drow) * R_0 + r_0 + 64 + dc]) = s1;
        __syncthreads();
#pragma unroll
        for (int p = 0; p < 4; p++) cf[p] = nf[p];
        c_0 = c0; r_0 = r0; R_0 = R; d_0 = dst;
      }
#undef SETJOB
      return;
    }
    gid = xcd * 24 + lid;
  }

  const int chunk = gid / gxy, rem = gid % gxy;
  const int gpc = gy << 3;
  const int band = rem / gpc, r2 = rem % gpc;
  const int bm = (band * 8 + (r2 & 7)) * 256;
  const int bn = (r2 >> 3) * 256;

  const bf16* Ab = A + (size_t)bm * K;
  const bf16* Bb = Bt + (size_t)bn * K;

  const int lr = lane >> 3;
  const int sle = ((lane & 7) ^ lr) * 8;
  const int rB0 = w * 16;
  const int rB1 = 128 + w * 16;
  const int rA0 = wm * 128 + wn * 16;
  const int rA1 = wm * 128 + 64 + wn * 16;

  const int rowA = (wm * 128 + fr) * 128;
  const int rowB = (wn * 64 + fr) * 128;
  const int colk0 = (g * 16) ^ ((fr & 7) << 4);
  const int colk1 = (64 + g * 16) ^ ((fr & 7) << 4);

  f32x4 acc[8][4] = {};

#define SG8(base, r0, kb, ldsrow)                                           \
  do {                                                                      \
    gload_lds16(base + (size_t)((r0) + lr) * K + (kb) + sle, (ldsrow));     \
    gload_lds16(base + (size_t)((r0) + 8 + lr) * K + (kb) + sle,            \
                (char*)(ldsrow) + 1024);                                    \
  } while (0)

  const int nt = Kc >> 6;
  const int koff = chunk * Kc;

  SG8(Bb, rB0, koff, BsB + rB0 * 128);
  SG8(Bb, rB1, koff, BsB + rB1 * 128);
  SG8(Ab, rA0, koff, AsB + rA0 * 128);
  SG8(Ab, rA1, koff, AsB + rA1 * 128);

#define PHASE_BODY(p, mb)                                                     \
  {                                                                           \
    if ((p) == 0) {                                                           \
      _Pragma("unroll") for (int nf = 0; nf < 4; nf++) {                      \
        bfr[nf][0] = *(const bf16x8*)(Br + rowB + nf * 2048 + colk0);         \
        bfr[nf][1] = *(const bf16x8*)(Br + rowB + nf * 2048 + colk1);         \
      }                                                                       \
    }                                                                         \
    af[0][0] = *(const bf16x8*)(Ar + rowA + (mb)*2048 + colk0);               \
    af[0][1] = *(const bf16x8*)(Ar + rowA + (mb)*2048 + colk1);               \
    af[1][0] = *(const bf16x8*)(Ar + rowA + ((mb) + 1) * 2048 + colk0);       \
    af[1][1] = *(const bf16x8*)(Ar + rowA + ((mb) + 1) * 2048 + colk1);       \
    if (pre) {                                                                \
      if ((p) == 0) SG8(Bb, rB0, kb2, Bw + rB0 * 128);                        \
      if ((p) == 1) SG8(Bb, rB1, kb2, Bw + rB1 * 128);                        \
      if ((p) == 2) SG8(Ab, rA0, kb2, Aw + rA0 * 128);                        \
      if ((p) == 3) SG8(Ab, rA1, kb2, Aw + rA1 * 128);                        \
    }                                                                         \
    __builtin_amdgcn_s_setprio(1);                                            \
    _Pragma("unroll") for (int m2 = 0; m2 < 2; m2++)                          \
        _Pragma("unroll") for (int nf = 0; nf < 4; nf++) {                    \
      acc[(mb) + m2][nf] = __builtin_amdgcn_mfma_f32_16x16x32_bf16(           \
          af[m2][0], bfr[nf][0], acc[(mb) + m2][nf], 0, 0, 0);                \
      acc[(mb) + m2][nf] = __builtin_amdgcn_mfma_f32_16x16x32_bf16(           \
          af[m2][1], bfr[nf][1], acc[(mb) + m2][nf], 0, 0, 0);                \
    }                                                                         \
    __builtin_amdgcn_s_setprio(0);                                            \
  }

  int buf = 0;
  for (int kt = 0; kt < nt; ++kt) {
    char* Ar = AsB + buf * 32768;
    char* Br = BsB + buf * 32768;
    char* Aw = AsB + (buf ^ 1) * 32768;
    char* Bw = BsB + (buf ^ 1) * 32768;
    const bool pre = (kt + 1) < nt;
    const int kb2 = koff + (kt + 1) * 64;
    bf16x8 bfr[4][2];
    bf16x8 af[2][2];

    asm volatile("s_waitcnt vmcnt(2)" ::: "memory");
    __builtin_amdgcn_s_barrier();
    PHASE_BODY(0, 0)

    if (pre) asm volatile("s_waitcnt vmcnt(4)" ::: "memory");
    else     asm volatile("s_waitcnt vmcnt(2)" ::: "memory");
    __builtin_amdgcn_s_barrier();
    PHASE_BODY(1, 2)

    if (pre) asm volatile("s_waitcnt vmcnt(4)" ::: "memory");
    else     asm volatile("s_waitcnt vmcnt(0)" ::: "memory");
    __builtin_amdgcn_s_barrier();
    PHASE_BODY(2, 4)

    if (pre) asm volatile("s_waitcnt vmcnt(6)" ::: "memory");
    else     asm volatile("s_waitcnt vmcnt(0)" ::: "memory");
    __builtin_amdgcn_s_barrier();
    PHASE_BODY(3, 6)

    buf ^= 1;
  }
#undef PHASE_BODY
#undef SG8

  bf16* outp = (bf16*)Cout + (EPI == 3 ? (size_t)chunk * M * N : 0);
  const int cr = g * 4;
#pragma unroll
  for (int mf = 0; mf < 8; mf++) {
#pragma unroll
    for (int nf = 0; nf < 4; nf++) {
      const int row = bm + wm * 128 + mf * 16 + cr;
      const int col = bn + wn * 64 + nf * 16 + fr;
#pragma unroll
      for (int r = 0; r < 4; r++) {
        const float va = acc[mf][nf][r];
        const size_t idx = (size_t)(row + r) * N + col;
        if (EPI == 3 || EPI == 0) {
          outp[idx] = (bf16)va;
        } else {
          const float t = va + bias[col];
          outp[idx] = (bf16)(t > 0.f ? t : 0.f);
        }
      }
    }
  }
}

// ---------------- Flash attention v4 + T5 setprio around MFMA clusters ----------------
__global__ __launch_bounds__(512, 4) void attn_kernel(const bf16* __restrict__ Q,
                                                      const bf16* __restrict__ K,
                                                      const bf16* __restrict__ V,
                                                      bf16* __restrict__ O, int ld) {
  __shared__ __align__(16) bf16 Ks[2][64][64];
  __shared__ __align__(16) bf16 Vt[2][64][64];
  __shared__ __align__(16) bf16 Pl[8][16][64];
  const int tid = threadIdx.x;
  const int w = tid >> 6, l = tid & 63;
  const int lo = l & 15, g = l >> 4;
  const int sw = (lo & 7) << 3;

  const int id = blockIdx.x;
  const int bh = id & 63, qb = id >> 6;
  const int b = bh >> 4, h = bh & 15;
  const int hoff = h * 64;
  const size_t rowQ = (size_t)b * 1024 + qb * 128 + w * 16;
  const size_t rowKV0 = (size_t)b * 1024;

  const int srow = tid >> 3, scch = tid & 7;
  const int vcb = w * 8;

  bf16x8 qfr[2];
#pragma unroll
  for (int ds = 0; ds < 2; ds++)
    qfr[ds] = *reinterpret_cast<const bf16x8*>(
        Q + (rowQ + lo) * ld + hoff + ds * 32 + g * 8);

  const float c = 0.18033688f;  // 0.125 * log2(e)
  f32x4 lacc = {0.f, 0.f, 0.f, 0.f};
  f32x4 o[4] = {};

  {
    gload_lds16(K + (rowKV0 + srow) * ld + hoff + ((scch ^ (srow & 7)) << 3),
                &Ks[0][w * 8][0]);
    bf16x8 vv = *reinterpret_cast<const bf16x8*>(V + (rowKV0 + l) * ld + hoff + vcb);
#pragma unroll
    for (int j = 0; j < 8; j++) Vt[0][vcb + j][l ^ (j << 3)] = vv[j];
  }
  __syncthreads();

#define ATILE(PAR, KT)                                                               \
  {                                                                                  \
    bf16x8 vv;                                                                       \
    const bool more = (KT) + 1 < 16;                                                 \
    if (more) {                                                                      \
      const size_t rkv = rowKV0 + ((KT) + 1) * 64;                                   \
      gload_lds16(K + (rkv + srow) * ld + hoff + ((scch ^ (srow & 7)) << 3),         \
                  &Ks[(PAR) ^ 1][w * 8][0]);                                         \
      vv = *reinterpret_cast<const bf16x8*>(V + (rkv + l) * ld + hoff + vcb);        \
    }                                                                                \
    f32x4 sa[4] = {};                                                                \
    __builtin_amdgcn_s_setprio(1);                                                   \
    _Pragma("unroll") for (int ds = 0; ds < 2; ds++) {                               \
      bf16x8 kf[4];                                                                  \
      _Pragma("unroll") for (int kfi = 0; kfi < 4; kfi++)                            \
          kf[kfi] = *reinterpret_cast<const bf16x8*>(                                \
              &Ks[PAR][kfi * 16 + lo][(ds * 32 + g * 8) ^ sw]);                      \
      _Pragma("unroll") for (int kfi = 0; kfi < 4; kfi++)                            \
          sa[kfi] =                                                                  \
              __builtin_amdgcn_mfma_f32_16x16x32_bf16(kf[kfi], qfr[ds], sa[kfi], 0, 0, 0); \
    }                                                                                \
    __builtin_amdgcn_s_setprio(0);                                                   \
    float p[16];                                                                     \
    _Pragma("unroll") for (int kfi = 0; kfi < 4; kfi++)                              \
        _Pragma("unroll") for (int r = 0; r < 4; r++)                                \
            p[kfi * 4 + r] = exp2f(sa[kfi][r] * c);                                  \
    _Pragma("unroll") for (int r = 0; r < 4; r++)                                    \
        lacc[r] += (p[r] + p[4 + r]) + (p[8 + r] + p[12 + r]);                       \
    _Pragma("unroll") for (int kfi = 0; kfi < 4; kfi++) {                            \
      bf16x4 pk;                                                                     \
      pk[0] = (bf16)p[kfi * 4 + 0];                                                  \
      pk[1] = (bf16)p[kfi * 4 + 1];                                                  \
      pk[2] = (bf16)p[kfi * 4 + 2];                                                  \
      pk[3] = (bf16)p[kfi * 4 + 3];                                                  \
      *reinterpret_cast<bf16x4*>(&Pl[w][lo][(kfi * 16 + g * 4) ^ sw]) = pk;          \
    }                                                                                \
    __builtin_amdgcn_s_setprio(1);                                                   \
    _Pragma("unroll") for (int ks = 0; ks < 2; ks++) {                               \
      bf16x8 pf = *reinterpret_cast<const bf16x8*>(&Pl[w][lo][(ks * 32 + g * 8) ^ sw]); \
      _Pragma("unroll") for (int df = 0; df < 4; df++) {                             \
        bf16x8 vf = *reinterpret_cast<const bf16x8*>(                                \
            &Vt[PAR][df * 16 + lo][(ks * 32 + g * 8) ^ sw]);                         \
        o[df] = __builtin_amdgcn_mfma_f32_16x16x32_bf16(vf, pf, o[df], 0, 0, 0);     \
      }                                                                              \
    }                                                                                \
    __builtin_amdgcn_s_setprio(0);                                                   \
    if (more) {                                                                      \
      _Pragma("unroll") for (int j = 0; j < 8; j++)                                  \
          Vt[(PAR) ^ 1][vcb + j][l ^ (j << 3)] = vv[j];                              \
    }                                                                                \
    __syncthreads();                                                                 \
  }

  for (int kt2 = 0; kt2 < 16; kt2 += 2) {
    ATILE(0, kt2)
    ATILE(1, kt2 + 1)
  }
#undef ATILE

  float lsum = (lacc[0] + lacc[1]) + (lacc[2] + lacc[3]);
  lsum += __shfl_xor(lsum, 16);
  lsum += __shfl_xor(lsum, 32);
  const float rl = 1.f / lsum;
#pragma unroll
  for (int df = 0; df < 4; df++) {
    bf16x4 ov;
#pragma unroll
    for (int r = 0; r < 4; r++) ov[r] = (bf16)(o[df][r] * rl);
    *reinterpret_cast<bf16x4*>(&Pl[w][lo][(df * 16 + g * 4) ^ sw]) = ov;
  }
  const int row = l >> 2;
  const int swr = (row & 7) << 3;
  const int c2 = (l & 3) * 16;
#pragma unroll
  for (int i = 0; i < 2; i++) {
    bf16x8 ov = *reinterpret_cast<const bf16x8*>(&Pl[w][row][(c2 + i * 8) ^ swr]);
    *reinterpret_cast<bf16x8*>(O + (rowQ + row) * 1024 + hoff + c2 + i * 8) = ov;
  }
}

// --------------------------------- launch -------------------------------------------
extern "C" void kernel_launch(void* const* d_in, const int* in_sizes, int n_in,
                              void* d_out, int out_size, void* d_ws, size_t ws_size,
                              hipStream_t stream) {
  const float* x     = (const float*)d_in[0];
  const float* ln1_g = (const float*)d_in[1];
  const float* ln1_b = (const float*)d_in[2];
  const float* wq    = (const float*)d_in[3];
  const float* wk    = (const float*)d_in[4];
  const float* wv    = (const float*)d_in[5];
  const float* wo    = (const float*)d_in[6];
  const float* ln2_g = (const float*)d_in[7];
  const float* ln2_b = (const float*)d_in[8];
  const float* w1    = (const float*)d_in[9];
  const float* b1    = (const float*)d_in[10];
  const float* w2    = (const float*)d_in[11];
  const float* b2    = (const float*)d_in[12];

  const size_t MB = 1ull << 20;
  char* ws = (char*)d_ws;
  bf16* wTqkv = (bf16*)(ws + 0 * MB);    // 6MB
  bf16* wTo   = (bf16*)(ws + 6 * MB);    // 2MB
  bf16* wT1   = (bf16*)(ws + 8 * MB);    // 8MB
  bf16* wT2   = (bf16*)(ws + 16 * MB);   // 8MB
  bf16* x1    = (bf16*)(ws + 24 * MB);   // 8MB; attn out aliases; FFN2 p0 later
  bf16* qkv   = (bf16*)(ws + 32 * MB);   // 24MB; x2 / FFN2 p1-p3 alias
  bf16* xres  = (bf16*)(ws + 56 * MB);   // 8MB bf16 trunk
  bf16* h1    = (bf16*)(ws + 72 * MB);   // 32MB
  bf16* attn  = x1;
  bf16* x2    = qkv;
  bf16* pOp   = (bf16*)(ws + 40 * MB);   // o-proj partials: 2 x 8MB at [40,56)
  bf16* pF    = (bf16*)(ws + 24 * MB);   // FFN2 partials: 4 x 8MB at [24,56)

  const dim3 TB(256);

  // prologue: LN1 + qkv/o weight transposes (w1/w2 ride inside the QKV GEMM)
  prep_kernel<<<5120, TB, 0, stream>>>(wq, wk, wv, wo, wTqkv, wTo,
                                       x, ln1_g, ln1_b, x1);

  // fused QKV projection (24 GEMM + 8 aux blocks per XCD)
  gemm256<0><<<256, dim3(512), 0, stream>>>(x1, wTqkv, qkv, nullptr,
                                            4096, 3072, 1024, 12, 192, 1024, 64,
                                            w1, w2, wT1, wT2);

  // attention: 512 blocks x 512 threads (8 waves x 16q)
  attn_kernel<<<512, dim3(512), 0, stream>>>(qkv, qkv + 1024, qkv + 2048, attn, 3072);

  // O projection: 128^2 2-phase split-K=2, grid 512 -> bf16 partials
  gemm_bt<3><<<512, TB, 0, stream>>>(attn, wTo, pOp, nullptr, 4096, 1024, 1024, 8, 256, 512);

  // fused: xres = bf16(p0+p1+x) ; x2 = LN2(fp32 sum)
  reduce_ln_kernel<<<1024, TB, 0, stream>>>(pOp, pOp + 4096 * 1024, x, ln2_g, ln2_b, xres, x2);

  // FFN1: relu(x2 @ w1 + b1) -> bf16; 256^2 8-phase, grid 256
  gemm256<2><<<256, dim3(512), 0, stream>>>(x2, wT1, h1, b1,
                                            4096, 4096, 1024, 16, 256, 1024, 0,
                                            nullptr, nullptr, nullptr, nullptr);

  // FFN2 split-K=4: 256^2 8-phase, grid 256 -> bf16 partials
  gemm256<3><<<256, dim3(512), 0, stream>>>(h1, wT2, pF, nullptr,
                                            4096, 1024, 4096, 4, 64, 1024, 0,
                                            nullptr, nullptr, nullptr, nullptr);

  // final: out = p0+p1+p2+p3 + b2 + xres
  reduce_out_kernel<<<2048, TB, 0, stream>>>(pF, pF + 4096 * 1024, pF + 2 * 4096 * 1024,
                                             pF + 3 * 4096 * 1024, b2, xres, (float*)d_out);
}